// Round 9
// baseline (302.592 us; speedup 1.0000x reference)
//
#include <hip/hip_runtime.h>

// SiameseGNN round 28: pipeline consolidation. agg kernels untouched
// (measured floor: ~2.1 TB/s random-gather path, 4 rounds of evidence).
//
// R27 evidence: agg1 back at 52.8us (floor); total 278.7. agg1+agg2
// ~103us; bottom-up estimates for the rest fall short of ~175us ->
// big slice is pipeline structure (9 dependent dispatches + redundant
// passes + 1-wave fc).
//   fix 1: gemm1 FUSED into csrb (csrb owns the 128 nodes + dinv in
//          LDS; its 4 waves run the chunk's 8 MFMA tiles after the
//          csr scatter). One fewer dependent dispatch.
//   fix 2: rank-from-first-atomic in binA and csrb -- the histogram
//          atomicAdd return IS the placement rank; packed into spare
//          bits (dst:17, rank:13). Deletes binA's second 8K-LDS-atomic
//          pass (+rezero+barrier) and csrb's cur[] pass.
//   fix 3: colsum deleted -- agg2 atomicAdds its 64-float block row
//          into P2[b&511] (spread, non-returning); P2 zeroed in zeroCur.
//   fix 4: fc parallelized: 256 threads / 4 waves over rows (was 1
//          wave x 256 serial row loads).
// Dispatches 9 -> 7. Everything else = R27.

#define TPB    256
#define CHUNK  128
#define SHIFT  7
#define KMAX   1024
#define CAP    2560
#define EPB    8192
#define CPAD   16      // cursorG stride (ints)
#define P2R    512     // P2 accumulator rows

typedef __attribute__((ext_vector_type(8))) short short8;
typedef __attribute__((ext_vector_type(4))) float f32x4;
typedef __attribute__((ext_vector_type(2))) float float2v;
typedef __attribute__((ext_vector_type(2))) unsigned int uint2v;

struct Ctx {
    const float* X; const int* esrc; const int* edst;
    unsigned int* temp; unsigned char* Hs2; unsigned char* Hs;
    unsigned int* csr; int* row_ptr; int* degA; float* dinv; int* cursorG;
    float* P2; float* outp;
};

__device__ __forceinline__ unsigned short f2bf(float x) {
    union { float f; unsigned int i; } c; c.f = x;
    unsigned int r = c.i + 0x7FFFu + ((c.i >> 16) & 1u);   // RNE
    return (unsigned short)(r >> 16);
}
__device__ __forceinline__ unsigned char f2fp8(float x) {
    int p = __builtin_amdgcn_cvt_pk_fp8_f32(x, x, 0, false);
    return (unsigned char)(p & 0xFF);
}
__device__ __forceinline__ float2v up8lo(unsigned int w) {
    return __builtin_amdgcn_cvt_pk_f32_fp8(w, false);
}
__device__ __forceinline__ float2v up8hi(unsigned int w) {
    return __builtin_amdgcn_cvt_pk_f32_fp8(w, true);
}

__global__ void k_prepW2(const float* __restrict__ W1, const float* __restrict__ W2,
                         unsigned short* __restrict__ Wt1, unsigned short* __restrict__ Wt2) {
    const float* W = blockIdx.x ? W2 : W1;
    unsigned short* Wt = blockIdx.x ? Wt2 : Wt1;
    for (int i = threadIdx.x; i < 64 * 64; i += 256) {
        int n = i >> 6, k = i & 63;
        Wt[i] = f2bf(W[k * 64 + n]);
    }
}

// zero cursors + P2 accumulator + the Hs sentinel row (row N)
__global__ void k_zeroCur(Ctx c0, Ctx c1, int nb0, int K, int N) {
    int b = blockIdx.x; Ctx c = c0;
    if (b >= nb0) { c = c1; b -= nb0; }
    int i = b * blockDim.x + threadIdx.x;
    if (i < K) c.cursorG[i * CPAD] = 0;
    if (b == 0 && threadIdx.x < 64) c.Hs[(size_t)N * 64 + threadIdx.x] = 0;
    int stride = nb0 * blockDim.x;
    for (int j = i; j < P2R * 64; j += stride) c.P2[j] = 0.0f;
}

// binA: LDS counting sort per block, burst segment writes. 1024 threads.
// R28: rank captured from the histogram atomicAdd (packed dst|rank<<17)
// -- second atomic pass, cnt rezero, and one barrier deleted.
__global__ __launch_bounds__(1024) void k_binA(Ctx c0, Ctx c1, int nb0, int E, int K) {
    __shared__ int cnt[KMAX];
    __shared__ int ofs[KMAX];
    __shared__ int segBase[KMAX];
    __shared__ int wsum[16];
    __shared__ unsigned int sorted[EPB];
    __shared__ unsigned short bkt[EPB];
    int b = blockIdx.x; Ctx c = c0;
    if (b >= nb0) { c = c1; b -= nb0; }
    int tid = threadIdx.x;               // 0..1023 == KMAX
    cnt[tid] = 0;
    __syncthreads();
    int base = b * EPB;
    int tot = E - base; if (tot > EPB) tot = EPB;
    unsigned int rd[EPB / 1024];
    unsigned int rs[EPB / 1024];
#pragma unroll
    for (int k = 0; k < EPB / 1024; ++k) {
        int e = base + k * 1024 + tid;
        rd[k] = 0xFFFFFFFFu; rs[k] = 0;
        if (e < E) {
            unsigned int dst = (unsigned int)c.edst[e];
            rs[k] = (unsigned int)c.esrc[e];
            unsigned int rk = (unsigned int)atomicAdd(&cnt[dst >> SHIFT], 1);
            rd[k] = dst | (rk << 17);    // dst:17 bits (N<131072), rank:13
        }
    }
    __syncthreads();
    int v = cnt[tid];
    int lane = tid & 63, w = tid >> 6;
    int x = v;                            // wave-inclusive scan
#pragma unroll
    for (int off = 1; off < 64; off <<= 1) {
        int t = __shfl_up(x, off, 64);
        if (lane >= off) x += t;
    }
    if (lane == 63) wsum[w] = x;
    __syncthreads();
    if (tid < 16) {
        int y = wsum[tid];
#pragma unroll
        for (int off = 1; off < 16; off <<= 1) {
            int t = __shfl_up(y, off, 16);
            if ((tid & 15) >= off) y += t;
        }
        wsum[tid] = y;                    // inclusive wave totals
    }
    __syncthreads();
    int pre = w ? wsum[w - 1] : 0;
    ofs[tid] = x + pre - v;               // exclusive scan
    if (tid < K) {
        segBase[tid] = v ? atomicAdd(&c.cursorG[tid * CPAD], v) : 0;
    } else {
        segBase[tid] = 0;
    }
    __syncthreads();
#pragma unroll
    for (int k = 0; k < EPB / 1024; ++k) {
        if (rd[k] != 0xFFFFFFFFu) {
            unsigned int dst = rd[k] & 0x1FFFFu;
            int rk = (int)(rd[k] >> 17);
            int bk = (int)(dst >> SHIFT);
            int p = ofs[bk] + rk;
            sorted[p] = ((dst & (CHUNK - 1)) << 17) | rs[k];
            bkt[p] = (unsigned short)bk;
        }
    }
    __syncthreads();
    for (int p = tid; p < tot; p += 1024) {
        unsigned int vv = sorted[p];
        int bk = bkt[p];
        int pos = segBase[bk] + (p - ofs[bk]);
        if (pos < CAP) c.temp[(size_t)bk * CAP + pos] = vv;
    }
}

// Shared MFMA body: A-fragments provided; B from Wt; store fp8 Hs.
__device__ __forceinline__ void mfma_tail(short8 a0, short8 a1,
                                          const unsigned short* __restrict__ Wt,
                                          unsigned char* __restrict__ Hs,
                                          int row0, int r, int q, int N) {
    short8 bfrag[4][2];
#pragma unroll
    for (int ct = 0; ct < 4; ++ct)
#pragma unroll
        for (int kb = 0; kb < 2; ++kb)
            bfrag[ct][kb] = *(const short8*)(Wt + (ct * 16 + r) * 64 + q * 8 + 32 * kb);
    f32x4 acc[4];
#pragma unroll
    for (int ct = 0; ct < 4; ++ct) {
        acc[ct] = (f32x4){0.0f, 0.0f, 0.0f, 0.0f};
        acc[ct] = __builtin_amdgcn_mfma_f32_16x16x32_bf16(a0, bfrag[ct][0], acc[ct], 0, 0, 0);
        acc[ct] = __builtin_amdgcn_mfma_f32_16x16x32_bf16(a1, bfrag[ct][1], acc[ct], 0, 0, 0);
    }
#pragma unroll
    for (int reg = 0; reg < 4; ++reg) {
        int row = row0 + q * 4 + reg;
        if (row < N) {
            size_t base = (size_t)row * 64 + r;
#pragma unroll
            for (int ct = 0; ct < 4; ++ct)
                Hs[base + ct * 16] = f2fp8(acc[ct][reg]);
        }
    }
}

// Per-bucket LDS counting sort -> bucket-major csr slice (stride CAP) +
// row_ptr/deg/dinv + FUSED GEMM1 (the chunk's 8 MFMA tiles; dinv from
// LDS). Rank captured from the histogram atomicAdd (cur[] pass deleted).
__global__ __launch_bounds__(256) void k_csrb(Ctx c0, Ctx c1, int nb0,
                                              const unsigned short* __restrict__ Wt1,
                                              int N) {
    __shared__ int deg[CHUNK];
    __shared__ int lofs[CHUNK];
    __shared__ int wsum2[2];
    __shared__ float sdinv[CHUNK];
    __shared__ unsigned int tl[CAP];
    int b = blockIdx.x; Ctx c = c0;
    if (b >= nb0) { c = c1; b -= nb0; }
    int tid = threadIdx.x;
    if (tid < CHUNK) deg[tid] = 0;
    __syncthreads();
    int cnt = c.cursorG[b * CPAD]; if (cnt > CAP) cnt = CAP;
    const size_t tb = (size_t)b * CAP;
    int rkl[(CAP + 255) / 256];
    {
        int it = 0;
        for (int i = tid; i < cnt; i += 256, ++it) {
            unsigned int vv = c.temp[tb + i];
            tl[i] = vv;
            rkl[it] = atomicAdd(&deg[vv >> 17], 1);
        }
    }
    __syncthreads();
    int vdeg = 0, x = 0;
    if (tid < CHUNK) { vdeg = deg[tid]; x = vdeg; }
#pragma unroll
    for (int off = 1; off < 64; off <<= 1) {
        int t = __shfl_up(x, off, 64);
        if ((tid & 63) >= off) x += t;
    }
    if (tid < CHUNK && (tid & 63) == 63) wsum2[tid >> 6] = x;
    __syncthreads();
    int base = b * CAP;                  // bucket-major: no global scan needed
    if (tid < CHUNK) {
        int pre = (tid >> 6) ? wsum2[0] : 0;
        int excl = x + pre - vdeg;
        lofs[tid] = excl;
        sdinv[tid] = rsqrtf((float)vdeg + 1.0f);
        int node = b * CHUNK + tid;
        if (node < N) {
            c.row_ptr[node] = base + excl;
            c.degA[node] = vdeg;
            c.dinv[node] = sdinv[tid];
        }
    }
    __syncthreads();
    {
        int it = 0;
        for (int i = tid; i < cnt; i += 256, ++it) {
            unsigned int p = tl[i];
            int dl = p >> 17;
            c.csr[base + lofs[dl] + rkl[it]] = (p & 0x1FFFFu) << 6;   // src byte off
        }
    }
    // FUSED GEMM1: wave w handles tiles w and w+4 of this chunk.
    int wave = tid >> 6, lane = tid & 63;
    int r = lane & 15, q = lane >> 4;
#pragma unroll
    for (int tt = 0; tt < 2; ++tt) {
        int row0 = b * CHUNK + (wave + tt * 4) * 16;
        if (row0 < N) {
            int row = row0 + r;
            int rr = row < N ? row : N - 1;          // clamp stays in-chunk
            float d = sdinv[rr - b * CHUNK];
            const float* xrow = c.X + (size_t)rr * 64 + q * 8;
            short8 a0, a1;
#pragma unroll
            for (int j = 0; j < 8; ++j) a0[j] = (short)f2bf(xrow[j] * d);
#pragma unroll
            for (int j = 0; j < 8; ++j) a1[j] = (short)f2bf(xrow[32 + j] * d);
            mfma_tail(a0, a1, Wt1, c.Hs, row0, r, q, N);
        }
    }
}

// agg block mapping: XCD-partition swizzle (graph = (blockIdx>>2)&1) when
// swz, else linear split.
__device__ __forceinline__ void agg_map(int bi, int nb0, int swz,
                                        const Ctx& c0, const Ctx& c1,
                                        Ctx& c, int& b) {
    if (swz) {
        int graph = (bi >> 2) & 1;
        b = ((bi >> 3) << 2) | (bi & 3);
        c = graph ? c1 : c0;
    } else {
        b = bi; c = c0;
        if (b >= nb0) { c = c1; b -= nb0; }
    }
}

// 8-deep dwordx2 issue/consume windows; one window = 32 slots (4 edges
// per wave-instruction: 8 subgroups x 8 lanes x 8B). slotbase
// compile-time, lim scalar (SGPR).
__device__ __forceinline__ void agg_issue8w(const unsigned char* __restrict__ Hs,
                                            unsigned int idx, int lim,
                                            int hbase, int j, unsigned int s8,
                                            uint2v* h) {
#pragma unroll
    for (int u = 0; u < 8; ++u) {
        if (4 * u >= lim) break;              // SGPR cmp -> s_cbranch
        unsigned int su = (unsigned int)__shfl((int)idx, hbase + 4 * u + j, 64);
        h[u] = *(const uint2v*)(Hs + (su | s8));
    }
}
__device__ __forceinline__ void agg_cons8w(const uint2v* h, int lim, float2v* acc) {
#pragma unroll
    for (int u = 0; u < 8; ++u) {
        if (4 * u >= lim) break;
        acc[0] += up8lo(h[u][0]); acc[1] += up8hi(h[u][0]);   // sentinel adds 0
        acc[2] += up8lo(h[u][1]); acc[3] += up8hi(h[u][1]);
    }
}

// Two node-pairs per wave, pipelined: both cold idx loads overlap; both
// pairs' first windows are in flight before the first wait. Per half: 4
// subgroups x 8 lanes; lane s covers fp8 channels 8s..8s+7. csr holds
// src<<6; gather offset = su | (s*8). Invalid slots -> sentinel N<<6.
__device__ __forceinline__ void agg_pair2(const unsigned char* __restrict__ Hs,
                                          const unsigned int* __restrict__ csr,
                                          int beg0, int deg0, int maxs0,
                                          int beg1, int deg1, int maxs1,
                                          int lane, unsigned int sent,
                                          float2v* acc0, float2v* acc1) {
    int hbase = lane & 32;
    int hl = lane & 31;
    int j = (hl >> 3) & 3;
    unsigned int s8 = (unsigned int)((lane & 7) * 8);
    unsigned int idx0 = (hl < deg0) ? csr[beg0 + hl] : sent;
    unsigned int idx1 = (hl < deg1) ? csr[beg1 + hl] : sent;
    int lim0 = maxs0 > 32 ? 32 : maxs0;   // scalar
    int lim1 = maxs1 > 32 ? 32 : maxs1;   // scalar
    uint2v h0[8], h1[8];
    agg_issue8w(Hs, idx0, lim0, hbase, j, s8, h0);
    agg_issue8w(Hs, idx1, lim1, hbase, j, s8, h1);
    agg_cons8w(h0, lim0, acc0);
    agg_cons8w(h1, lim1, acc1);
    // rare deep tails (deg > 32)
    for (int base = 32; base < maxs0; base += 32) {
        unsigned int idx = (base + hl < deg0) ? csr[beg0 + base + hl] : sent;
        int lim = maxs0 - base; if (lim > 32) lim = 32;
        uint2v hh[8];
        agg_issue8w(Hs, idx, lim, hbase, j, s8, hh);
        agg_cons8w(hh, lim, acc0);
    }
    for (int base = 32; base < maxs1; base += 32) {
        unsigned int idx = (base + hl < deg1) ? csr[beg1 + base + hl] : sent;
        int lim = maxs1 - base; if (lim > 32) lim = 32;
        uint2v hh[8];
        agg_issue8w(Hs, idx, lim, hbase, j, s8, hh);
        agg_cons8w(hh, lim, acc1);
    }
    // merge the half's 4 subgroups (bits 3,4); does not cross halves
#pragma unroll
    for (int k = 0; k < 4; ++k) {
        float2v o;
        o.x = __shfl_xor(acc0[k].x, 8, 64);  o.y = __shfl_xor(acc0[k].y, 8, 64);
        acc0[k] += o;
        o.x = __shfl_xor(acc0[k].x, 16, 64); o.y = __shfl_xor(acc0[k].y, 16, 64);
        acc0[k] += o;
        o.x = __shfl_xor(acc1[k].x, 8, 64);  o.y = __shfl_xor(acc1[k].y, 8, 64);
        acc1[k] += o;
        o.x = __shfl_xor(acc1[k].x, 16, 64); o.y = __shfl_xor(acc1[k].y, 16, 64);
        acc1[k] += o;
    }
}

// layer-1 + fused GEMM2: block = 16 nodes (4 waves x 2 pairs). v = dinv *
// relu(b + dinv * agg); rows staged in LDS bf16 (XOR-swizzled at
// 8-element granularity), one barrier, each wave MFMAs one 16-col tile
// of W2, stores fp8 Hs2. Hs2 sentinel row N zeroed here (aliases temp).
__global__ __launch_bounds__(256, 8) void k_agg1(Ctx c0, Ctx c1, int nb0, int swz,
                                                 const float* __restrict__ bias,
                                                 const unsigned short* __restrict__ Wt2,
                                                 int n) {
    __shared__ unsigned short As[16][64];
    Ctx c; int b;
    agg_map(blockIdx.x, nb0, swz, c0, c1, c, b);
    int wave = threadIdx.x >> 6, lane = threadIdx.x & 63;
    int h = lane >> 5;
    int nbase = b * 16 + wave * 4;
    int node0 = nbase + h;
    int node1 = nbase + 2 + h;
    int nd0 = node0 < n ? node0 : 0;
    int nd1 = node1 < n ? node1 : 0;
    int beg0 = c.row_ptr[nd0];
    int beg1 = c.row_ptr[nd1];
    int deg0 = (node0 < n) ? c.degA[nd0] : 0;
    int deg1 = (node1 < n) ? c.degA[nd1] : 0;
    int od0 = __shfl_xor(deg0, 32, 64); int m0 = deg0 > od0 ? deg0 : od0;
    int od1 = __shfl_xor(deg1, 32, 64); int m1 = deg1 > od1 ? deg1 : od1;
    int maxs0 = __builtin_amdgcn_readfirstlane(m0);
    int maxs1 = __builtin_amdgcn_readfirstlane(m1);
    if (b == 0 && threadIdx.x < 64) c.Hs2[(size_t)n * 64 + threadIdx.x] = 0;
    float2v acc0[4] = {{0.f,0.f},{0.f,0.f},{0.f,0.f},{0.f,0.f}};
    float2v acc1[4] = {{0.f,0.f},{0.f,0.f},{0.f,0.f},{0.f,0.f}};
    agg_pair2(c.Hs, c.csr, beg0, deg0, maxs0, beg1, deg1, maxs1,
              lane, (unsigned int)n << 6, acc0, acc1);
    if (((lane >> 3) & 3) == 0) {          // first subgroup of each half
        int s = lane & 7;
#pragma unroll
        for (int pr = 0; pr < 2; ++pr) {
            const float2v* ac = pr ? acc1 : acc0;
            int node = nbase + pr * 2 + h;
            ushort4 oA = {0, 0, 0, 0}, oB = {0, 0, 0, 0};
            if (node < n) {
                uint2v hv = *(const uint2v*)(c.Hs + (size_t)node * 64 + s * 8);
                float2v h0 = up8lo(hv[0]), h1 = up8hi(hv[0]);
                float2v h2 = up8lo(hv[1]), h3 = up8hi(hv[1]);
                float4 ba = *(const float4*)(bias + s * 8);
                float4 bb = *(const float4*)(bias + s * 8 + 4);
                float d = c.dinv[node];
                oA.x = f2bf(fmaxf(ba.x + d * (ac[0].x + h0.x), 0.0f) * d);
                oA.y = f2bf(fmaxf(ba.y + d * (ac[0].y + h0.y), 0.0f) * d);
                oA.z = f2bf(fmaxf(ba.z + d * (ac[1].x + h1.x), 0.0f) * d);
                oA.w = f2bf(fmaxf(ba.w + d * (ac[1].y + h1.y), 0.0f) * d);
                oB.x = f2bf(fmaxf(bb.x + d * (ac[2].x + h2.x), 0.0f) * d);
                oB.y = f2bf(fmaxf(bb.y + d * (ac[2].y + h2.y), 0.0f) * d);
                oB.z = f2bf(fmaxf(bb.z + d * (ac[3].x + h3.x), 0.0f) * d);
                oB.w = f2bf(fmaxf(bb.w + d * (ac[3].y + h3.y), 0.0f) * d);
            }
            int row = wave * 4 + pr * 2 + h;
            int col = (s * 8) ^ ((row & 7) << 3);
            *(ushort4*)(&As[row][col]) = oA;       // swizzled (8-elem blocks)
            *(ushort4*)(&As[row][col + 4]) = oB;
        }
    }
    __syncthreads();
    // fused GEMM2: wave handles col-tile ct = wave; all 16 A rows valid.
    {
        int r = lane & 15, q = lane >> 4;
        int sw = (r & 7) << 3;
        short8 a0 = *(const short8*)(&As[r][(q * 8) ^ sw]);
        short8 a1 = *(const short8*)(&As[r][(q * 8 + 32) ^ sw]);
        const unsigned short* wp = Wt2 + (wave * 16 + r) * 64 + q * 8;
        short8 b0 = *(const short8*)(wp);
        short8 b1 = *(const short8*)(wp + 32);
        f32x4 acc2 = {0.0f, 0.0f, 0.0f, 0.0f};
        acc2 = __builtin_amdgcn_mfma_f32_16x16x32_bf16(a0, b0, acc2, 0, 0, 0);
        acc2 = __builtin_amdgcn_mfma_f32_16x16x32_bf16(a1, b1, acc2, 0, 0, 0);
#pragma unroll
        for (int reg = 0; reg < 4; ++reg) {
            int l = q * 4 + reg;                     // local row 0..15
            int row = b * 16 + l;
            if (row < n)
                c.Hs2[(size_t)row * 64 + wave * 16 + r] = f2fp8(acc2[reg]);
        }
    }
}

// layer-2: block = 16 nodes; block-reduce 16 relu'd rows and atomicAdd
// the 64-float row into P2[b & (P2R-1)] (colsum kernel deleted).
__global__ __launch_bounds__(256, 8) void k_agg2(Ctx c0, Ctx c1, int nb0, int swz,
                                                 const float* __restrict__ bias, int n) {
    __shared__ float red[16 * 64];
    Ctx c; int b;
    agg_map(blockIdx.x, nb0, swz, c0, c1, c, b);
    int wave = threadIdx.x >> 6, lane = threadIdx.x & 63;
    int h = lane >> 5;
    int nbase = b * 16 + wave * 4;
    int node0 = nbase + h;
    int node1 = nbase + 2 + h;
    int nd0 = node0 < n ? node0 : 0;
    int nd1 = node1 < n ? node1 : 0;
    int beg0 = c.row_ptr[nd0];
    int beg1 = c.row_ptr[nd1];
    int deg0 = (node0 < n) ? c.degA[nd0] : 0;
    int deg1 = (node1 < n) ? c.degA[nd1] : 0;
    int od0 = __shfl_xor(deg0, 32, 64); int m0 = deg0 > od0 ? deg0 : od0;
    int od1 = __shfl_xor(deg1, 32, 64); int m1 = deg1 > od1 ? deg1 : od1;
    int maxs0 = __builtin_amdgcn_readfirstlane(m0);
    int maxs1 = __builtin_amdgcn_readfirstlane(m1);
    float2v acc0[4] = {{0.f,0.f},{0.f,0.f},{0.f,0.f},{0.f,0.f}};
    float2v acc1[4] = {{0.f,0.f},{0.f,0.f},{0.f,0.f},{0.f,0.f}};
    agg_pair2(c.Hs2, c.csr, beg0, deg0, maxs0, beg1, deg1, maxs1,
              lane, (unsigned int)n << 6, acc0, acc1);
    if (((lane >> 3) & 3) == 0) {
        int s = lane & 7;
#pragma unroll
        for (int pr = 0; pr < 2; ++pr) {
            const float2v* ac = pr ? acc1 : acc0;
            int node = nbase + pr * 2 + h;
            float4 vA = {0.f, 0.f, 0.f, 0.f}, vB = {0.f, 0.f, 0.f, 0.f};
            if (node < n) {
                uint2v hv = *(const uint2v*)(c.Hs2 + (size_t)node * 64 + s * 8);
                float2v h0 = up8lo(hv[0]), h1 = up8hi(hv[0]);
                float2v h2 = up8lo(hv[1]), h3 = up8hi(hv[1]);
                float4 ba = *(const float4*)(bias + s * 8);
                float4 bb = *(const float4*)(bias + s * 8 + 4);
                float d = c.dinv[node];
                vA.x = fmaxf(ba.x + d * (ac[0].x + h0.x), 0.0f);
                vA.y = fmaxf(ba.y + d * (ac[0].y + h0.y), 0.0f);
                vA.z = fmaxf(ba.z + d * (ac[1].x + h1.x), 0.0f);
                vA.w = fmaxf(ba.w + d * (ac[1].y + h1.y), 0.0f);
                vB.x = fmaxf(bb.x + d * (ac[2].x + h2.x), 0.0f);
                vB.y = fmaxf(bb.y + d * (ac[2].y + h2.y), 0.0f);
                vB.z = fmaxf(bb.z + d * (ac[3].x + h3.x), 0.0f);
                vB.w = fmaxf(bb.w + d * (ac[3].y + h3.y), 0.0f);
            }
            int row = wave * 4 + pr * 2 + h;
            *(float4*)(&red[row * 64 + s * 8]) = vA;
            *(float4*)(&red[row * 64 + s * 8 + 4]) = vB;
        }
    }
    __syncthreads();
    if (threadIdx.x < 64) {
        float acc16 = 0.0f;
#pragma unroll
        for (int r = 0; r < 16; ++r) acc16 += red[r * 64 + threadIdx.x];
        atomicAdd(&c.P2[(b & (P2R - 1)) * 64 + threadIdx.x], acc16);
    }
}

// fc: 4-wave row-parallel reduce of P2, then out = fcb + (S/n) @ fcw^T
__global__ __launch_bounds__(256) void k_fc(Ctx c0, Ctx c1,
                                            const float* __restrict__ fcw,
                                            const float* __restrict__ fcb, int n) {
    Ctx c = blockIdx.x ? c1 : c0;
    __shared__ float Sp[4][64];
    int j = threadIdx.x & 63, g = threadIdx.x >> 6;
    float s = 0.0f;
    for (int r = g; r < P2R; r += 4) s += c.P2[r * 64 + j];
    Sp[g][j] = s;
    __syncthreads();
    if (threadIdx.x < 64) {
        float S = (Sp[0][j] + Sp[1][j]) + (Sp[2][j] + Sp[3][j]);
        Sp[0][j] = S * (1.0f / (float)n);
    }
    __syncthreads();
    if (threadIdx.x < 64) {
        float acc = fcb[j];
#pragma unroll
        for (int k = 0; k < 64; ++k) acc += Sp[0][k] * fcw[j * 64 + k];
        c.outp[j] = acc;
    }
}

extern "C" void kernel_launch(void* const* d_in, const int* in_sizes, int n_in,
                              void* d_out, int out_size, void* d_ws, size_t ws_size,
                              hipStream_t stream) {
    const float* x[2]  = {(const float*)d_in[0], (const float*)d_in[1]};
    const int*   ei[2] = {(const int*)d_in[2], (const int*)d_in[3]};
    const float* W1  = (const float*)d_in[4];
    const float* b1  = (const float*)d_in[5];
    const float* W2  = (const float*)d_in[6];
    const float* b2  = (const float*)d_in[7];
    const float* fcw = (const float*)d_in[8];
    const float* fcb = (const float*)d_in[9];
    float* out = (float*)d_out;

    const int N  = in_sizes[0] / 64;
    const int E  = in_sizes[2] / 2;
    const int NF = N * 64;
    const int K  = (N + CHUNK - 1) / CHUNK;     // 782 buckets
    const int gGm  = (N + 15) / 16;             // aggregate blocks (16 nodes each)
    const int gGmP = (gGm + 3) & ~3;            // padded so swizzle stays legal
    const int gBin = (E + EPB - 1) / EPB;
    const int gK  = (K + TPB - 1) / TPB;

    auto al = [](size_t x) { return (x + 127) & ~(size_t)127; };
    size_t tempB = (size_t)K * CAP * 4;
    size_t hs2B  = (size_t)NF + 64;                    // fp8 + sentinel row N
    size_t szRegion = al(tempB > hs2B ? tempB : hs2B); // Hs2 aliases temp
    size_t szHs  = al((size_t)NF + 64);                // fp8 + sentinel row N
    size_t szCsr = al((size_t)K * CAP * 4);            // bucket-major, stride CAP
    size_t szRp  = al((size_t)N * 4);                  // beg only
    size_t szDeg = al((size_t)N * 4);
    size_t szDi  = al((size_t)N * 4);
    size_t szCu  = al((size_t)K * CPAD * 4);           // padded cursors
    size_t szP2  = al((size_t)P2R * 64 * 4);
    size_t setB  = szRegion + szHs + szCsr + szRp + szDeg + szDi + szCu + szP2;
    size_t wtB   = 2 * al(64 * 64 * 2);
    bool batched = ws_size >= wtB + 2 * setB;

    char* base = (char*)d_ws;
    unsigned short* Wt1 = (unsigned short*)base;
    unsigned short* Wt2 = (unsigned short*)(base + al(64 * 64 * 2));

    auto mkctx = [&](int g, char* p) {
        Ctx c;
        c.X = x[g]; c.esrc = ei[g]; c.edst = ei[g] + E;
        c.temp = (unsigned int*)p; c.Hs2 = (unsigned char*)p; p += szRegion;
        c.Hs = (unsigned char*)p; p += szHs;
        c.csr = (unsigned int*)p; p += szCsr;
        c.row_ptr = (int*)p; p += szRp;
        c.degA = (int*)p; p += szDeg;
        c.dinv = (float*)p; p += szDi;
        c.cursorG = (int*)p; p += szCu;
        c.P2 = (float*)p;
        c.outp = out + g * 64;
        return c;
    };
    char* set0 = base + wtB;
    Ctx c0 = mkctx(0, set0);
    Ctx c1 = mkctx(1, batched ? set0 + setB : set0);   // fallback: shares set0

    k_prepW2<<<2, 256, 0, stream>>>(W1, W2, Wt1, Wt2);

    auto pipe = [&](Ctx A, Ctx B, int mult) {
        int swz = (mult == 2) ? 1 : 0;   // gGmP is always %4 == 0
        k_zeroCur<<<mult * gK, TPB, 0, stream>>>(A, B, gK, K, N);
        k_binA<<<mult * gBin, 1024, 0, stream>>>(A, B, gBin, E, K);
        k_csrb<<<mult * K, 256, 0, stream>>>(A, B, K, Wt1, N);
        k_agg1<<<mult * gGmP, 256, 0, stream>>>(A, B, gGmP, swz, b1, Wt2, N);
        k_agg2<<<mult * gGmP, 256, 0, stream>>>(A, B, gGmP, swz, b2, N);
        k_fc<<<mult, 256, 0, stream>>>(A, B, fcw, fcb, N);
    };

    if (batched) {
        pipe(c0, c1, 2);
    } else {
        pipe(c0, c0, 1);   // sequential, shared buffer set
        pipe(c1, c1, 1);
    }
}

// Round 11
// 298.227 us; speedup vs baseline: 1.0146x; 1.0146x over previous
//
#include <hip/hip_runtime.h>

// SiameseGNN round 30: resubmit of R29 (bench infra failed: "container
// failed twice" -- no data, kernel unmeasured). No changes.
//
// R28 evidence: total 278.7 -> 302.6 (+24us) while agg1 byte-identical
// at 52.8us -- the regression is in the restructured kernels. Cause:
// csrb's rkl[] rank array is indexed by a runtime loop counter (trip
// count = cnt) -> compiler allocates it in SCRATCH (rule: runtime-indexed
// arrays go to local memory); every histogram iter pays a scratch store,
// every scatter iter a scratch load, x1564 blocks.
//   fix: csrb back to the R27-proven two-pass LDS form -- stage tl[] in
//        LDS during the histogram (temp still read ONCE from global),
//        scatter with cur[] LDS-atomic ranks. gemm1 fusion tail kept.
// Everything else = R28 (binA rank-from-atomic in compile-time-indexed
// registers, colsum deleted via agg2->P2 atomics, 4-wave fc, 7
// dispatches, agg kernels at their measured ~2.1 TB/s gather floor).

#define TPB    256
#define CHUNK  128
#define SHIFT  7
#define KMAX   1024
#define CAP    2560
#define EPB    8192
#define CPAD   16      // cursorG stride (ints)
#define P2R    512     // P2 accumulator rows

typedef __attribute__((ext_vector_type(8))) short short8;
typedef __attribute__((ext_vector_type(4))) float f32x4;
typedef __attribute__((ext_vector_type(2))) float float2v;
typedef __attribute__((ext_vector_type(2))) unsigned int uint2v;

struct Ctx {
    const float* X; const int* esrc; const int* edst;
    unsigned int* temp; unsigned char* Hs2; unsigned char* Hs;
    unsigned int* csr; int* row_ptr; int* degA; float* dinv; int* cursorG;
    float* P2; float* outp;
};

__device__ __forceinline__ unsigned short f2bf(float x) {
    union { float f; unsigned int i; } c; c.f = x;
    unsigned int r = c.i + 0x7FFFu + ((c.i >> 16) & 1u);   // RNE
    return (unsigned short)(r >> 16);
}
__device__ __forceinline__ unsigned char f2fp8(float x) {
    int p = __builtin_amdgcn_cvt_pk_fp8_f32(x, x, 0, false);
    return (unsigned char)(p & 0xFF);
}
__device__ __forceinline__ float2v up8lo(unsigned int w) {
    return __builtin_amdgcn_cvt_pk_f32_fp8(w, false);
}
__device__ __forceinline__ float2v up8hi(unsigned int w) {
    return __builtin_amdgcn_cvt_pk_f32_fp8(w, true);
}

__global__ void k_prepW2(const float* __restrict__ W1, const float* __restrict__ W2,
                         unsigned short* __restrict__ Wt1, unsigned short* __restrict__ Wt2) {
    const float* W = blockIdx.x ? W2 : W1;
    unsigned short* Wt = blockIdx.x ? Wt2 : Wt1;
    for (int i = threadIdx.x; i < 64 * 64; i += 256) {
        int n = i >> 6, k = i & 63;
        Wt[i] = f2bf(W[k * 64 + n]);
    }
}

// zero cursors + P2 accumulator + the Hs sentinel row (row N)
__global__ void k_zeroCur(Ctx c0, Ctx c1, int nb0, int K, int N) {
    int b = blockIdx.x; Ctx c = c0;
    if (b >= nb0) { c = c1; b -= nb0; }
    int i = b * blockDim.x + threadIdx.x;
    if (i < K) c.cursorG[i * CPAD] = 0;
    if (b == 0 && threadIdx.x < 64) c.Hs[(size_t)N * 64 + threadIdx.x] = 0;
    int stride = nb0 * blockDim.x;
    for (int j = i; j < P2R * 64; j += stride) c.P2[j] = 0.0f;
}

// binA: LDS counting sort per block, burst segment writes. 1024 threads.
// Rank captured from the histogram atomicAdd (packed dst|rank<<17);
// rd/rs live in registers (compile-time-indexed unrolled loops only).
__global__ __launch_bounds__(1024) void k_binA(Ctx c0, Ctx c1, int nb0, int E, int K) {
    __shared__ int cnt[KMAX];
    __shared__ int ofs[KMAX];
    __shared__ int segBase[KMAX];
    __shared__ int wsum[16];
    __shared__ unsigned int sorted[EPB];
    __shared__ unsigned short bkt[EPB];
    int b = blockIdx.x; Ctx c = c0;
    if (b >= nb0) { c = c1; b -= nb0; }
    int tid = threadIdx.x;               // 0..1023 == KMAX
    cnt[tid] = 0;
    __syncthreads();
    int base = b * EPB;
    int tot = E - base; if (tot > EPB) tot = EPB;
    unsigned int rd[EPB / 1024];
    unsigned int rs[EPB / 1024];
#pragma unroll
    for (int k = 0; k < EPB / 1024; ++k) {
        int e = base + k * 1024 + tid;
        rd[k] = 0xFFFFFFFFu; rs[k] = 0;
        if (e < E) {
            unsigned int dst = (unsigned int)c.edst[e];
            rs[k] = (unsigned int)c.esrc[e];
            unsigned int rk = (unsigned int)atomicAdd(&cnt[dst >> SHIFT], 1);
            rd[k] = dst | (rk << 17);    // dst:17 bits (N<131072), rank:13
        }
    }
    __syncthreads();
    int v = cnt[tid];
    int lane = tid & 63, w = tid >> 6;
    int x = v;                            // wave-inclusive scan
#pragma unroll
    for (int off = 1; off < 64; off <<= 1) {
        int t = __shfl_up(x, off, 64);
        if (lane >= off) x += t;
    }
    if (lane == 63) wsum[w] = x;
    __syncthreads();
    if (tid < 16) {
        int y = wsum[tid];
#pragma unroll
        for (int off = 1; off < 16; off <<= 1) {
            int t = __shfl_up(y, off, 16);
            if ((tid & 15) >= off) y += t;
        }
        wsum[tid] = y;                    // inclusive wave totals
    }
    __syncthreads();
    int pre = w ? wsum[w - 1] : 0;
    ofs[tid] = x + pre - v;               // exclusive scan
    if (tid < K) {
        segBase[tid] = v ? atomicAdd(&c.cursorG[tid * CPAD], v) : 0;
    } else {
        segBase[tid] = 0;
    }
    __syncthreads();
#pragma unroll
    for (int k = 0; k < EPB / 1024; ++k) {
        if (rd[k] != 0xFFFFFFFFu) {
            unsigned int dst = rd[k] & 0x1FFFFu;
            int rk = (int)(rd[k] >> 17);
            int bk = (int)(dst >> SHIFT);
            int p = ofs[bk] + rk;
            sorted[p] = ((dst & (CHUNK - 1)) << 17) | rs[k];
            bkt[p] = (unsigned short)bk;
        }
    }
    __syncthreads();
    for (int p = tid; p < tot; p += 1024) {
        unsigned int vv = sorted[p];
        int bk = bkt[p];
        int pos = segBase[bk] + (p - ofs[bk]);
        if (pos < CAP) c.temp[(size_t)bk * CAP + pos] = vv;
    }
}

// Shared MFMA body: A-fragments provided; B from Wt; store fp8 Hs.
__device__ __forceinline__ void mfma_tail(short8 a0, short8 a1,
                                          const unsigned short* __restrict__ Wt,
                                          unsigned char* __restrict__ Hs,
                                          int row0, int r, int q, int N) {
    short8 bfrag[4][2];
#pragma unroll
    for (int ct = 0; ct < 4; ++ct)
#pragma unroll
        for (int kb = 0; kb < 2; ++kb)
            bfrag[ct][kb] = *(const short8*)(Wt + (ct * 16 + r) * 64 + q * 8 + 32 * kb);
    f32x4 acc[4];
#pragma unroll
    for (int ct = 0; ct < 4; ++ct) {
        acc[ct] = (f32x4){0.0f, 0.0f, 0.0f, 0.0f};
        acc[ct] = __builtin_amdgcn_mfma_f32_16x16x32_bf16(a0, bfrag[ct][0], acc[ct], 0, 0, 0);
        acc[ct] = __builtin_amdgcn_mfma_f32_16x16x32_bf16(a1, bfrag[ct][1], acc[ct], 0, 0, 0);
    }
#pragma unroll
    for (int reg = 0; reg < 4; ++reg) {
        int row = row0 + q * 4 + reg;
        if (row < N) {
            size_t base = (size_t)row * 64 + r;
#pragma unroll
            for (int ct = 0; ct < 4; ++ct)
                Hs[base + ct * 16] = f2fp8(acc[ct][reg]);
        }
    }
}

// Per-bucket LDS counting sort -> bucket-major csr slice (stride CAP) +
// row_ptr/deg/dinv + FUSED GEMM1 (the chunk's 8 MFMA tiles; dinv from
// LDS). Two-pass LDS form (R27-proven): tl[] staged during histogram
// (temp read once), scatter via cur[] LDS-atomic ranks -- NO register
// rank array (R28's runtime-indexed rkl[] went to scratch).
__global__ __launch_bounds__(256) void k_csrb(Ctx c0, Ctx c1, int nb0,
                                              const unsigned short* __restrict__ Wt1,
                                              int N) {
    __shared__ int deg[CHUNK];
    __shared__ int lofs[CHUNK];
    __shared__ int cur[CHUNK];
    __shared__ int wsum2[2];
    __shared__ float sdinv[CHUNK];
    __shared__ unsigned int tl[CAP];
    int b = blockIdx.x; Ctx c = c0;
    if (b >= nb0) { c = c1; b -= nb0; }
    int tid = threadIdx.x;
    if (tid < CHUNK) deg[tid] = 0;
    __syncthreads();
    int cnt = c.cursorG[b * CPAD]; if (cnt > CAP) cnt = CAP;
    const size_t tb = (size_t)b * CAP;
    for (int i = tid; i < cnt; i += 256) {
        unsigned int vv = c.temp[tb + i];
        tl[i] = vv;
        atomicAdd(&deg[vv >> 17], 1);
    }
    __syncthreads();
    int vdeg = 0, x = 0;
    if (tid < CHUNK) { vdeg = deg[tid]; x = vdeg; }
#pragma unroll
    for (int off = 1; off < 64; off <<= 1) {
        int t = __shfl_up(x, off, 64);
        if ((tid & 63) >= off) x += t;
    }
    if (tid < CHUNK && (tid & 63) == 63) wsum2[tid >> 6] = x;
    __syncthreads();
    int base = b * CAP;                  // bucket-major: no global scan needed
    if (tid < CHUNK) {
        int pre = (tid >> 6) ? wsum2[0] : 0;
        int excl = x + pre - vdeg;
        lofs[tid] = excl;
        cur[tid] = 0;
        sdinv[tid] = rsqrtf((float)vdeg + 1.0f);
        int node = b * CHUNK + tid;
        if (node < N) {
            c.row_ptr[node] = base + excl;
            c.degA[node] = vdeg;
            c.dinv[node] = sdinv[tid];
        }
    }
    __syncthreads();
    for (int i = tid; i < cnt; i += 256) {
        unsigned int p = tl[i];
        int dl = p >> 17;
        int rank = atomicAdd(&cur[dl], 1);
        c.csr[base + lofs[dl] + rank] = (p & 0x1FFFFu) << 6;   // src byte off
    }
    // FUSED GEMM1: wave w handles tiles w and w+4 of this chunk.
    int wave = tid >> 6, lane = tid & 63;
    int r = lane & 15, q = lane >> 4;
#pragma unroll
    for (int tt = 0; tt < 2; ++tt) {
        int row0 = b * CHUNK + (wave + tt * 4) * 16;
        if (row0 < N) {
            int row = row0 + r;
            int rr = row < N ? row : N - 1;          // clamp stays in-chunk
            float d = sdinv[rr - b * CHUNK];
            const float* xrow = c.X + (size_t)rr * 64 + q * 8;
            short8 a0, a1;
#pragma unroll
            for (int j = 0; j < 8; ++j) a0[j] = (short)f2bf(xrow[j] * d);
#pragma unroll
            for (int j = 0; j < 8; ++j) a1[j] = (short)f2bf(xrow[32 + j] * d);
            mfma_tail(a0, a1, Wt1, c.Hs, row0, r, q, N);
        }
    }
}

// agg block mapping: XCD-partition swizzle (graph = (blockIdx>>2)&1) when
// swz, else linear split.
__device__ __forceinline__ void agg_map(int bi, int nb0, int swz,
                                        const Ctx& c0, const Ctx& c1,
                                        Ctx& c, int& b) {
    if (swz) {
        int graph = (bi >> 2) & 1;
        b = ((bi >> 3) << 2) | (bi & 3);
        c = graph ? c1 : c0;
    } else {
        b = bi; c = c0;
        if (b >= nb0) { c = c1; b -= nb0; }
    }
}

// 8-deep dwordx2 issue/consume windows; one window = 32 slots (4 edges
// per wave-instruction: 8 subgroups x 8 lanes x 8B). slotbase
// compile-time, lim scalar (SGPR).
__device__ __forceinline__ void agg_issue8w(const unsigned char* __restrict__ Hs,
                                            unsigned int idx, int lim,
                                            int hbase, int j, unsigned int s8,
                                            uint2v* h) {
#pragma unroll
    for (int u = 0; u < 8; ++u) {
        if (4 * u >= lim) break;              // SGPR cmp -> s_cbranch
        unsigned int su = (unsigned int)__shfl((int)idx, hbase + 4 * u + j, 64);
        h[u] = *(const uint2v*)(Hs + (su | s8));
    }
}
__device__ __forceinline__ void agg_cons8w(const uint2v* h, int lim, float2v* acc) {
#pragma unroll
    for (int u = 0; u < 8; ++u) {
        if (4 * u >= lim) break;
        acc[0] += up8lo(h[u][0]); acc[1] += up8hi(h[u][0]);   // sentinel adds 0
        acc[2] += up8lo(h[u][1]); acc[3] += up8hi(h[u][1]);
    }
}

// Two node-pairs per wave, pipelined: both cold idx loads overlap; both
// pairs' first windows are in flight before the first wait. Per half: 4
// subgroups x 8 lanes; lane s covers fp8 channels 8s..8s+7. csr holds
// src<<6; gather offset = su | (s*8). Invalid slots -> sentinel N<<6.
__device__ __forceinline__ void agg_pair2(const unsigned char* __restrict__ Hs,
                                          const unsigned int* __restrict__ csr,
                                          int beg0, int deg0, int maxs0,
                                          int beg1, int deg1, int maxs1,
                                          int lane, unsigned int sent,
                                          float2v* acc0, float2v* acc1) {
    int hbase = lane & 32;
    int hl = lane & 31;
    int j = (hl >> 3) & 3;
    unsigned int s8 = (unsigned int)((lane & 7) * 8);
    unsigned int idx0 = (hl < deg0) ? csr[beg0 + hl] : sent;
    unsigned int idx1 = (hl < deg1) ? csr[beg1 + hl] : sent;
    int lim0 = maxs0 > 32 ? 32 : maxs0;   // scalar
    int lim1 = maxs1 > 32 ? 32 : maxs1;   // scalar
    uint2v h0[8], h1[8];
    agg_issue8w(Hs, idx0, lim0, hbase, j, s8, h0);
    agg_issue8w(Hs, idx1, lim1, hbase, j, s8, h1);
    agg_cons8w(h0, lim0, acc0);
    agg_cons8w(h1, lim1, acc1);
    // rare deep tails (deg > 32)
    for (int base = 32; base < maxs0; base += 32) {
        unsigned int idx = (base + hl < deg0) ? csr[beg0 + base + hl] : sent;
        int lim = maxs0 - base; if (lim > 32) lim = 32;
        uint2v hh[8];
        agg_issue8w(Hs, idx, lim, hbase, j, s8, hh);
        agg_cons8w(hh, lim, acc0);
    }
    for (int base = 32; base < maxs1; base += 32) {
        unsigned int idx = (base + hl < deg1) ? csr[beg1 + base + hl] : sent;
        int lim = maxs1 - base; if (lim > 32) lim = 32;
        uint2v hh[8];
        agg_issue8w(Hs, idx, lim, hbase, j, s8, hh);
        agg_cons8w(hh, lim, acc1);
    }
    // merge the half's 4 subgroups (bits 3,4); does not cross halves
#pragma unroll
    for (int k = 0; k < 4; ++k) {
        float2v o;
        o.x = __shfl_xor(acc0[k].x, 8, 64);  o.y = __shfl_xor(acc0[k].y, 8, 64);
        acc0[k] += o;
        o.x = __shfl_xor(acc0[k].x, 16, 64); o.y = __shfl_xor(acc0[k].y, 16, 64);
        acc0[k] += o;
        o.x = __shfl_xor(acc1[k].x, 8, 64);  o.y = __shfl_xor(acc1[k].y, 8, 64);
        acc1[k] += o;
        o.x = __shfl_xor(acc1[k].x, 16, 64); o.y = __shfl_xor(acc1[k].y, 16, 64);
        acc1[k] += o;
    }
}

// layer-1 + fused GEMM2: block = 16 nodes (4 waves x 2 pairs). v = dinv *
// relu(b + dinv * agg); rows staged in LDS bf16 (XOR-swizzled at
// 8-element granularity), one barrier, each wave MFMAs one 16-col tile
// of W2, stores fp8 Hs2. Hs2 sentinel row N zeroed here (aliases temp).
__global__ __launch_bounds__(256, 8) void k_agg1(Ctx c0, Ctx c1, int nb0, int swz,
                                                 const float* __restrict__ bias,
                                                 const unsigned short* __restrict__ Wt2,
                                                 int n) {
    __shared__ unsigned short As[16][64];
    Ctx c; int b;
    agg_map(blockIdx.x, nb0, swz, c0, c1, c, b);
    int wave = threadIdx.x >> 6, lane = threadIdx.x & 63;
    int h = lane >> 5;
    int nbase = b * 16 + wave * 4;
    int node0 = nbase + h;
    int node1 = nbase + 2 + h;
    int nd0 = node0 < n ? node0 : 0;
    int nd1 = node1 < n ? node1 : 0;
    int beg0 = c.row_ptr[nd0];
    int beg1 = c.row_ptr[nd1];
    int deg0 = (node0 < n) ? c.degA[nd0] : 0;
    int deg1 = (node1 < n) ? c.degA[nd1] : 0;
    int od0 = __shfl_xor(deg0, 32, 64); int m0 = deg0 > od0 ? deg0 : od0;
    int od1 = __shfl_xor(deg1, 32, 64); int m1 = deg1 > od1 ? deg1 : od1;
    int maxs0 = __builtin_amdgcn_readfirstlane(m0);
    int maxs1 = __builtin_amdgcn_readfirstlane(m1);
    if (b == 0 && threadIdx.x < 64) c.Hs2[(size_t)n * 64 + threadIdx.x] = 0;
    float2v acc0[4] = {{0.f,0.f},{0.f,0.f},{0.f,0.f},{0.f,0.f}};
    float2v acc1[4] = {{0.f,0.f},{0.f,0.f},{0.f,0.f},{0.f,0.f}};
    agg_pair2(c.Hs, c.csr, beg0, deg0, maxs0, beg1, deg1, maxs1,
              lane, (unsigned int)n << 6, acc0, acc1);
    if (((lane >> 3) & 3) == 0) {          // first subgroup of each half
        int s = lane & 7;
#pragma unroll
        for (int pr = 0; pr < 2; ++pr) {
            const float2v* ac = pr ? acc1 : acc0;
            int node = nbase + pr * 2 + h;
            ushort4 oA = {0, 0, 0, 0}, oB = {0, 0, 0, 0};
            if (node < n) {
                uint2v hv = *(const uint2v*)(c.Hs + (size_t)node * 64 + s * 8);
                float2v h0 = up8lo(hv[0]), h1 = up8hi(hv[0]);
                float2v h2 = up8lo(hv[1]), h3 = up8hi(hv[1]);
                float4 ba = *(const float4*)(bias + s * 8);
                float4 bb = *(const float4*)(bias + s * 8 + 4);
                float d = c.dinv[node];
                oA.x = f2bf(fmaxf(ba.x + d * (ac[0].x + h0.x), 0.0f) * d);
                oA.y = f2bf(fmaxf(ba.y + d * (ac[0].y + h0.y), 0.0f) * d);
                oA.z = f2bf(fmaxf(ba.z + d * (ac[1].x + h1.x), 0.0f) * d);
                oA.w = f2bf(fmaxf(ba.w + d * (ac[1].y + h1.y), 0.0f) * d);
                oB.x = f2bf(fmaxf(bb.x + d * (ac[2].x + h2.x), 0.0f) * d);
                oB.y = f2bf(fmaxf(bb.y + d * (ac[2].y + h2.y), 0.0f) * d);
                oB.z = f2bf(fmaxf(bb.z + d * (ac[3].x + h3.x), 0.0f) * d);
                oB.w = f2bf(fmaxf(bb.w + d * (ac[3].y + h3.y), 0.0f) * d);
            }
            int row = wave * 4 + pr * 2 + h;
            int col = (s * 8) ^ ((row & 7) << 3);
            *(ushort4*)(&As[row][col]) = oA;       // swizzled (8-elem blocks)
            *(ushort4*)(&As[row][col + 4]) = oB;
        }
    }
    __syncthreads();
    // fused GEMM2: wave handles col-tile ct = wave; all 16 A rows valid.
    {
        int r = lane & 15, q = lane >> 4;
        int sw = (r & 7) << 3;
        short8 a0 = *(const short8*)(&As[r][(q * 8) ^ sw]);
        short8 a1 = *(const short8*)(&As[r][(q * 8 + 32) ^ sw]);
        const unsigned short* wp = Wt2 + (wave * 16 + r) * 64 + q * 8;
        short8 b0 = *(const short8*)(wp);
        short8 b1 = *(const short8*)(wp + 32);
        f32x4 acc2 = {0.0f, 0.0f, 0.0f, 0.0f};
        acc2 = __builtin_amdgcn_mfma_f32_16x16x32_bf16(a0, b0, acc2, 0, 0, 0);
        acc2 = __builtin_amdgcn_mfma_f32_16x16x32_bf16(a1, b1, acc2, 0, 0, 0);
#pragma unroll
        for (int reg = 0; reg < 4; ++reg) {
            int l = q * 4 + reg;                     // local row 0..15
            int row = b * 16 + l;
            if (row < n)
                c.Hs2[(size_t)row * 64 + wave * 16 + r] = f2fp8(acc2[reg]);
        }
    }
}

// layer-2: block = 16 nodes; block-reduce 16 relu'd rows and atomicAdd
// the 64-float row into P2[b & (P2R-1)] (colsum kernel deleted).
__global__ __launch_bounds__(256, 8) void k_agg2(Ctx c0, Ctx c1, int nb0, int swz,
                                                 const float* __restrict__ bias, int n) {
    __shared__ float red[16 * 64];
    Ctx c; int b;
    agg_map(blockIdx.x, nb0, swz, c0, c1, c, b);
    int wave = threadIdx.x >> 6, lane = threadIdx.x & 63;
    int h = lane >> 5;
    int nbase = b * 16 + wave * 4;
    int node0 = nbase + h;
    int node1 = nbase + 2 + h;
    int nd0 = node0 < n ? node0 : 0;
    int nd1 = node1 < n ? node1 : 0;
    int beg0 = c.row_ptr[nd0];
    int beg1 = c.row_ptr[nd1];
    int deg0 = (node0 < n) ? c.degA[nd0] : 0;
    int deg1 = (node1 < n) ? c.degA[nd1] : 0;
    int od0 = __shfl_xor(deg0, 32, 64); int m0 = deg0 > od0 ? deg0 : od0;
    int od1 = __shfl_xor(deg1, 32, 64); int m1 = deg1 > od1 ? deg1 : od1;
    int maxs0 = __builtin_amdgcn_readfirstlane(m0);
    int maxs1 = __builtin_amdgcn_readfirstlane(m1);
    float2v acc0[4] = {{0.f,0.f},{0.f,0.f},{0.f,0.f},{0.f,0.f}};
    float2v acc1[4] = {{0.f,0.f},{0.f,0.f},{0.f,0.f},{0.f,0.f}};
    agg_pair2(c.Hs2, c.csr, beg0, deg0, maxs0, beg1, deg1, maxs1,
              lane, (unsigned int)n << 6, acc0, acc1);
    if (((lane >> 3) & 3) == 0) {
        int s = lane & 7;
#pragma unroll
        for (int pr = 0; pr < 2; ++pr) {
            const float2v* ac = pr ? acc1 : acc0;
            int node = nbase + pr * 2 + h;
            float4 vA = {0.f, 0.f, 0.f, 0.f}, vB = {0.f, 0.f, 0.f, 0.f};
            if (node < n) {
                uint2v hv = *(const uint2v*)(c.Hs2 + (size_t)node * 64 + s * 8);
                float2v h0 = up8lo(hv[0]), h1 = up8hi(hv[0]);
                float2v h2 = up8lo(hv[1]), h3 = up8hi(hv[1]);
                float4 ba = *(const float4*)(bias + s * 8);
                float4 bb = *(const float4*)(bias + s * 8 + 4);
                float d = c.dinv[node];
                vA.x = fmaxf(ba.x + d * (ac[0].x + h0.x), 0.0f);
                vA.y = fmaxf(ba.y + d * (ac[0].y + h0.y), 0.0f);
                vA.z = fmaxf(ba.z + d * (ac[1].x + h1.x), 0.0f);
                vA.w = fmaxf(ba.w + d * (ac[1].y + h1.y), 0.0f);
                vB.x = fmaxf(bb.x + d * (ac[2].x + h2.x), 0.0f);
                vB.y = fmaxf(bb.y + d * (ac[2].y + h2.y), 0.0f);
                vB.z = fmaxf(bb.z + d * (ac[3].x + h3.x), 0.0f);
                vB.w = fmaxf(bb.w + d * (ac[3].y + h3.y), 0.0f);
            }
            int row = wave * 4 + pr * 2 + h;
            *(float4*)(&red[row * 64 + s * 8]) = vA;
            *(float4*)(&red[row * 64 + s * 8 + 4]) = vB;
        }
    }
    __syncthreads();
    if (threadIdx.x < 64) {
        float acc16 = 0.0f;
#pragma unroll
        for (int r = 0; r < 16; ++r) acc16 += red[r * 64 + threadIdx.x];
        atomicAdd(&c.P2[(b & (P2R - 1)) * 64 + threadIdx.x], acc16);
    }
}

// fc: 4-wave row-parallel reduce of P2, then out = fcb + (S/n) @ fcw^T
__global__ __launch_bounds__(256) void k_fc(Ctx c0, Ctx c1,
                                            const float* __restrict__ fcw,
                                            const float* __restrict__ fcb, int n) {
    Ctx c = blockIdx.x ? c1 : c0;
    __shared__ float Sp[4][64];
    int j = threadIdx.x & 63, g = threadIdx.x >> 6;
    float s = 0.0f;
    for (int r = g; r < P2R; r += 4) s += c.P2[r * 64 + j];
    Sp[g][j] = s;
    __syncthreads();
    if (threadIdx.x < 64) {
        float S = (Sp[0][j] + Sp[1][j]) + (Sp[2][j] + Sp[3][j]);
        Sp[0][j] = S * (1.0f / (float)n);
    }
    __syncthreads();
    if (threadIdx.x < 64) {
        float acc = fcb[j];
#pragma unroll
        for (int k = 0; k < 64; ++k) acc += Sp[0][k] * fcw[j * 64 + k];
        c.outp[j] = acc;
    }
}

extern "C" void kernel_launch(void* const* d_in, const int* in_sizes, int n_in,
                              void* d_out, int out_size, void* d_ws, size_t ws_size,
                              hipStream_t stream) {
    const float* x[2]  = {(const float*)d_in[0], (const float*)d_in[1]};
    const int*   ei[2] = {(const int*)d_in[2], (const int*)d_in[3]};
    const float* W1  = (const float*)d_in[4];
    const float* b1  = (const float*)d_in[5];
    const float* W2  = (const float*)d_in[6];
    const float* b2  = (const float*)d_in[7];
    const float* fcw = (const float*)d_in[8];
    const float* fcb = (const float*)d_in[9];
    float* out = (float*)d_out;

    const int N  = in_sizes[0] / 64;
    const int E  = in_sizes[2] / 2;
    const int NF = N * 64;
    const int K  = (N + CHUNK - 1) / CHUNK;     // 782 buckets
    const int gGm  = (N + 15) / 16;             // aggregate blocks (16 nodes each)
    const int gGmP = (gGm + 3) & ~3;            // padded so swizzle stays legal
    const int gBin = (E + EPB - 1) / EPB;
    const int gK  = (K + TPB - 1) / TPB;

    auto al = [](size_t x) { return (x + 127) & ~(size_t)127; };
    size_t tempB = (size_t)K * CAP * 4;
    size_t hs2B  = (size_t)NF + 64;                    // fp8 + sentinel row N
    size_t szRegion = al(tempB > hs2B ? tempB : hs2B); // Hs2 aliases temp
    size_t szHs  = al((size_t)NF + 64);                // fp8 + sentinel row N
    size_t szCsr = al((size_t)K * CAP * 4);            // bucket-major, stride CAP
    size_t szRp  = al((size_t)N * 4);                  // beg only
    size_t szDeg = al((size_t)N * 4);
    size_t szDi  = al((size_t)N * 4);
    size_t szCu  = al((size_t)K * CPAD * 4);           // padded cursors
    size_t szP2  = al((size_t)P2R * 64 * 4);
    size_t setB  = szRegion + szHs + szCsr + szRp + szDeg + szDi + szCu + szP2;
    size_t wtB   = 2 * al(64 * 64 * 2);
    bool batched = ws_size >= wtB + 2 * setB;

    char* base = (char*)d_ws;
    unsigned short* Wt1 = (unsigned short*)base;
    unsigned short* Wt2 = (unsigned short*)(base + al(64 * 64 * 2));

    auto mkctx = [&](int g, char* p) {
        Ctx c;
        c.X = x[g]; c.esrc = ei[g]; c.edst = ei[g] + E;
        c.temp = (unsigned int*)p; c.Hs2 = (unsigned char*)p; p += szRegion;
        c.Hs = (unsigned char*)p; p += szHs;
        c.csr = (unsigned int*)p; p += szCsr;
        c.row_ptr = (int*)p; p += szRp;
        c.degA = (int*)p; p += szDeg;
        c.dinv = (float*)p; p += szDi;
        c.cursorG = (int*)p; p += szCu;
        c.P2 = (float*)p;
        c.outp = out + g * 64;
        return c;
    };
    char* set0 = base + wtB;
    Ctx c0 = mkctx(0, set0);
    Ctx c1 = mkctx(1, batched ? set0 + setB : set0);   // fallback: shares set0

    k_prepW2<<<2, 256, 0, stream>>>(W1, W2, Wt1, Wt2);

    auto pipe = [&](Ctx A, Ctx B, int mult) {
        int swz = (mult == 2) ? 1 : 0;   // gGmP is always %4 == 0
        k_zeroCur<<<mult * gK, TPB, 0, stream>>>(A, B, gK, K, N);
        k_binA<<<mult * gBin, 1024, 0, stream>>>(A, B, gBin, E, K);
        k_csrb<<<mult * K, 256, 0, stream>>>(A, B, K, Wt1, N);
        k_agg1<<<mult * gGmP, 256, 0, stream>>>(A, B, gGmP, swz, b1, Wt2, N);
        k_agg2<<<mult * gGmP, 256, 0, stream>>>(A, B, gGmP, swz, b2, N);
        k_fc<<<mult, 256, 0, stream>>>(A, B, fcw, fcb, N);
    };

    if (batched) {
        pipe(c0, c1, 2);
    } else {
        pipe(c0, c0, 1);   // sequential, shared buffer set
        pipe(c1, c1, 1);
    }
}

// Round 14
// 297.729 us; speedup vs baseline: 1.0163x; 1.0017x over previous
//
#include <hip/hip_runtime.h>

// SiameseGNN round 33: resubmit of R31/R32 (two consecutive infra
// failures: GPUAcquisitionTimeout -- no data, kernel still unmeasured).
// No changes.
//
// Evidence chain: R27=278.7 -> R28=302.6 (consolidation) -> R29/R30=298.2
// (csrb scratch fix recovered only 4.4us). agg1 byte-stable at 52.8us all
// rounds => ~19.5us regression lives in the consolidation set. Prime
// suspect: gemm1-into-csrb fusion -- standalone gemm1 streams X at t=0
// across ~1600 blocks (BW-bound); fused, each block's X loads wait on the
// serial histogram->scan->scatter path (latency-bound tail). Fusion
// REMOVED overlap.
//   this round: csrb = exact R27 (two-pass LDS, no gemm tail); k_gemm1
//   standalone again. KEEP the safe, work-strictly-decreasing subset:
//   - binA rank-from-atomic (deletes 2nd 8K-LDS-atomic pass/block)
//   - colsum deleted (agg2 -> spread non-returning P2[b&511] atomics)
//   - 4-wave parallel fc
// 7 dispatches. agg kernels untouched (measured ~2.1 TB/s gather floor).

#define TPB    256
#define CHUNK  128
#define SHIFT  7
#define KMAX   1024
#define CAP    2560
#define EPB    8192
#define CPAD   16      // cursorG stride (ints)
#define P2R    512     // P2 accumulator rows

typedef __attribute__((ext_vector_type(8))) short short8;
typedef __attribute__((ext_vector_type(4))) float f32x4;
typedef __attribute__((ext_vector_type(2))) float float2v;
typedef __attribute__((ext_vector_type(2))) unsigned int uint2v;

struct Ctx {
    const float* X; const int* esrc; const int* edst;
    unsigned int* temp; unsigned char* Hs2; unsigned char* Hs;
    unsigned int* csr; int* row_ptr; int* degA; float* dinv; int* cursorG;
    float* P2; float* outp;
};

__device__ __forceinline__ unsigned short f2bf(float x) {
    union { float f; unsigned int i; } c; c.f = x;
    unsigned int r = c.i + 0x7FFFu + ((c.i >> 16) & 1u);   // RNE
    return (unsigned short)(r >> 16);
}
__device__ __forceinline__ unsigned char f2fp8(float x) {
    int p = __builtin_amdgcn_cvt_pk_fp8_f32(x, x, 0, false);
    return (unsigned char)(p & 0xFF);
}
__device__ __forceinline__ float2v up8lo(unsigned int w) {
    return __builtin_amdgcn_cvt_pk_f32_fp8(w, false);
}
__device__ __forceinline__ float2v up8hi(unsigned int w) {
    return __builtin_amdgcn_cvt_pk_f32_fp8(w, true);
}

__global__ void k_prepW2(const float* __restrict__ W1, const float* __restrict__ W2,
                         unsigned short* __restrict__ Wt1, unsigned short* __restrict__ Wt2) {
    const float* W = blockIdx.x ? W2 : W1;
    unsigned short* Wt = blockIdx.x ? Wt2 : Wt1;
    for (int i = threadIdx.x; i < 64 * 64; i += 256) {
        int n = i >> 6, k = i & 63;
        Wt[i] = f2bf(W[k * 64 + n]);
    }
}

// zero cursors + P2 accumulator + the Hs sentinel row (row N)
__global__ void k_zeroCur(Ctx c0, Ctx c1, int nb0, int K, int N) {
    int b = blockIdx.x; Ctx c = c0;
    if (b >= nb0) { c = c1; b -= nb0; }
    int i = b * blockDim.x + threadIdx.x;
    if (i < K) c.cursorG[i * CPAD] = 0;
    if (b == 0 && threadIdx.x < 64) c.Hs[(size_t)N * 64 + threadIdx.x] = 0;
    int stride = nb0 * blockDim.x;
    for (int j = i; j < P2R * 64; j += stride) c.P2[j] = 0.0f;
}

// binA: LDS counting sort per block, burst segment writes. 1024 threads.
// Rank captured from the histogram atomicAdd (packed dst|rank<<17);
// rd/rs live in registers (compile-time-indexed unrolled loops only).
__global__ __launch_bounds__(1024) void k_binA(Ctx c0, Ctx c1, int nb0, int E, int K) {
    __shared__ int cnt[KMAX];
    __shared__ int ofs[KMAX];
    __shared__ int segBase[KMAX];
    __shared__ int wsum[16];
    __shared__ unsigned int sorted[EPB];
    __shared__ unsigned short bkt[EPB];
    int b = blockIdx.x; Ctx c = c0;
    if (b >= nb0) { c = c1; b -= nb0; }
    int tid = threadIdx.x;               // 0..1023 == KMAX
    cnt[tid] = 0;
    __syncthreads();
    int base = b * EPB;
    int tot = E - base; if (tot > EPB) tot = EPB;
    unsigned int rd[EPB / 1024];
    unsigned int rs[EPB / 1024];
#pragma unroll
    for (int k = 0; k < EPB / 1024; ++k) {
        int e = base + k * 1024 + tid;
        rd[k] = 0xFFFFFFFFu; rs[k] = 0;
        if (e < E) {
            unsigned int dst = (unsigned int)c.edst[e];
            rs[k] = (unsigned int)c.esrc[e];
            unsigned int rk = (unsigned int)atomicAdd(&cnt[dst >> SHIFT], 1);
            rd[k] = dst | (rk << 17);    // dst:17 bits (N<131072), rank:13
        }
    }
    __syncthreads();
    int v = cnt[tid];
    int lane = tid & 63, w = tid >> 6;
    int x = v;                            // wave-inclusive scan
#pragma unroll
    for (int off = 1; off < 64; off <<= 1) {
        int t = __shfl_up(x, off, 64);
        if (lane >= off) x += t;
    }
    if (lane == 63) wsum[w] = x;
    __syncthreads();
    if (tid < 16) {
        int y = wsum[tid];
#pragma unroll
        for (int off = 1; off < 16; off <<= 1) {
            int t = __shfl_up(y, off, 16);
            if ((tid & 15) >= off) y += t;
        }
        wsum[tid] = y;                    // inclusive wave totals
    }
    __syncthreads();
    int pre = w ? wsum[w - 1] : 0;
    ofs[tid] = x + pre - v;               // exclusive scan
    if (tid < K) {
        segBase[tid] = v ? atomicAdd(&c.cursorG[tid * CPAD], v) : 0;
    } else {
        segBase[tid] = 0;
    }
    __syncthreads();
#pragma unroll
    for (int k = 0; k < EPB / 1024; ++k) {
        if (rd[k] != 0xFFFFFFFFu) {
            unsigned int dst = rd[k] & 0x1FFFFu;
            int rk = (int)(rd[k] >> 17);
            int bk = (int)(dst >> SHIFT);
            int p = ofs[bk] + rk;
            sorted[p] = ((dst & (CHUNK - 1)) << 17) | rs[k];
            bkt[p] = (unsigned short)bk;
        }
    }
    __syncthreads();
    for (int p = tid; p < tot; p += 1024) {
        unsigned int vv = sorted[p];
        int bk = bkt[p];
        int pos = segBase[bk] + (p - ofs[bk]);
        if (pos < CAP) c.temp[(size_t)bk * CAP + pos] = vv;
    }
}

// Per-bucket LDS counting sort -> bucket-major csr slice (stride CAP) +
// row_ptr (beg) + deg + dinv. Exact R27 form: tl[] staged during
// histogram (temp read once), scatter via cur[] LDS-atomic ranks.
__global__ __launch_bounds__(256) void k_csrb(Ctx c0, Ctx c1, int nb0, int N) {
    __shared__ int deg[CHUNK];
    __shared__ int lofs[CHUNK];
    __shared__ int cur[CHUNK];
    __shared__ int wsum2[2];
    __shared__ unsigned int tl[CAP];
    int b = blockIdx.x; Ctx c = c0;
    if (b >= nb0) { c = c1; b -= nb0; }
    int tid = threadIdx.x;
    if (tid < CHUNK) deg[tid] = 0;
    __syncthreads();
    int cnt = c.cursorG[b * CPAD]; if (cnt > CAP) cnt = CAP;
    const size_t tb = (size_t)b * CAP;
    for (int i = tid; i < cnt; i += 256) {
        unsigned int vv = c.temp[tb + i];
        tl[i] = vv;
        atomicAdd(&deg[vv >> 17], 1);
    }
    __syncthreads();
    int vdeg = 0, x = 0;
    if (tid < CHUNK) { vdeg = deg[tid]; x = vdeg; }
#pragma unroll
    for (int off = 1; off < 64; off <<= 1) {
        int t = __shfl_up(x, off, 64);
        if ((tid & 63) >= off) x += t;
    }
    if (tid < CHUNK && (tid & 63) == 63) wsum2[tid >> 6] = x;
    __syncthreads();
    int base = b * CAP;                  // bucket-major: no global scan needed
    if (tid < CHUNK) {
        int pre = (tid >> 6) ? wsum2[0] : 0;
        int excl = x + pre - vdeg;
        lofs[tid] = excl;
        cur[tid] = 0;
        int node = b * CHUNK + tid;
        if (node < N) {
            c.row_ptr[node] = base + excl;
            c.degA[node] = vdeg;
            c.dinv[node] = rsqrtf((float)vdeg + 1.0f);
        }
    }
    __syncthreads();
    for (int i = tid; i < cnt; i += 256) {
        unsigned int p = tl[i];
        int dl = p >> 17;
        int rank = atomicAdd(&cur[dl], 1);
        c.csr[base + lofs[dl] + rank] = (p & 0x1FFFFu) << 6;   // src byte offset
    }
}

// Shared MFMA body: A-fragments provided; B from Wt; store fp8 Hs.
__device__ __forceinline__ void mfma_tail(short8 a0, short8 a1,
                                          const unsigned short* __restrict__ Wt,
                                          unsigned char* __restrict__ Hs,
                                          int row0, int r, int q, int N) {
    short8 bfrag[4][2];
#pragma unroll
    for (int ct = 0; ct < 4; ++ct)
#pragma unroll
        for (int kb = 0; kb < 2; ++kb)
            bfrag[ct][kb] = *(const short8*)(Wt + (ct * 16 + r) * 64 + q * 8 + 32 * kb);
    f32x4 acc[4];
#pragma unroll
    for (int ct = 0; ct < 4; ++ct) {
        acc[ct] = (f32x4){0.0f, 0.0f, 0.0f, 0.0f};
        acc[ct] = __builtin_amdgcn_mfma_f32_16x16x32_bf16(a0, bfrag[ct][0], acc[ct], 0, 0, 0);
        acc[ct] = __builtin_amdgcn_mfma_f32_16x16x32_bf16(a1, bfrag[ct][1], acc[ct], 0, 0, 0);
    }
#pragma unroll
    for (int reg = 0; reg < 4; ++reg) {
        int row = row0 + q * 4 + reg;
        if (row < N) {
            size_t base = (size_t)row * 64 + r;
#pragma unroll
            for (int ct = 0; ct < 4; ++ct)
                Hs[base + ct * 16] = f2fp8(acc[ct][reg]);
        }
    }
}

// GEMM1 (standalone again): fp32 X in, dinv folded into A-fragment conv.
__global__ __launch_bounds__(256) void k_gemm1(Ctx c0, Ctx c1, int nb0,
                                               const unsigned short* __restrict__ Wt,
                                               int nTiles, int N) {
    int b = blockIdx.x; Ctx c = c0;
    if (b >= nb0) { c = c1; b -= nb0; }
    int wave = threadIdx.x >> 6, lane = threadIdx.x & 63;
    int tile = b * 4 + wave;
    if (tile >= nTiles) return;
    int r = lane & 15, q = lane >> 4;
    int row0 = tile * 16;
    int row = row0 + r;
    int rr = row < N ? row : N - 1;
    float d = c.dinv[rr];
    const float* xrow = c.X + (size_t)rr * 64 + q * 8;
    short8 a0, a1;
#pragma unroll
    for (int j = 0; j < 8; ++j) a0[j] = (short)f2bf(xrow[j] * d);
#pragma unroll
    for (int j = 0; j < 8; ++j) a1[j] = (short)f2bf(xrow[32 + j] * d);
    mfma_tail(a0, a1, Wt, c.Hs, row0, r, q, N);
}

// agg block mapping: XCD-partition swizzle (graph = (blockIdx>>2)&1) when
// swz, else linear split.
__device__ __forceinline__ void agg_map(int bi, int nb0, int swz,
                                        const Ctx& c0, const Ctx& c1,
                                        Ctx& c, int& b) {
    if (swz) {
        int graph = (bi >> 2) & 1;
        b = ((bi >> 3) << 2) | (bi & 3);
        c = graph ? c1 : c0;
    } else {
        b = bi; c = c0;
        if (b >= nb0) { c = c1; b -= nb0; }
    }
}

// 8-deep dwordx2 issue/consume windows; one window = 32 slots (4 edges
// per wave-instruction: 8 subgroups x 8 lanes x 8B). slotbase
// compile-time, lim scalar (SGPR).
__device__ __forceinline__ void agg_issue8w(const unsigned char* __restrict__ Hs,
                                            unsigned int idx, int lim,
                                            int hbase, int j, unsigned int s8,
                                            uint2v* h) {
#pragma unroll
    for (int u = 0; u < 8; ++u) {
        if (4 * u >= lim) break;              // SGPR cmp -> s_cbranch
        unsigned int su = (unsigned int)__shfl((int)idx, hbase + 4 * u + j, 64);
        h[u] = *(const uint2v*)(Hs + (su | s8));
    }
}
__device__ __forceinline__ void agg_cons8w(const uint2v* h, int lim, float2v* acc) {
#pragma unroll
    for (int u = 0; u < 8; ++u) {
        if (4 * u >= lim) break;
        acc[0] += up8lo(h[u][0]); acc[1] += up8hi(h[u][0]);   // sentinel adds 0
        acc[2] += up8lo(h[u][1]); acc[3] += up8hi(h[u][1]);
    }
}

// Two node-pairs per wave, pipelined: both cold idx loads overlap; both
// pairs' first windows are in flight before the first wait. Per half: 4
// subgroups x 8 lanes; lane s covers fp8 channels 8s..8s+7. csr holds
// src<<6; gather offset = su | (s*8). Invalid slots -> sentinel N<<6.
__device__ __forceinline__ void agg_pair2(const unsigned char* __restrict__ Hs,
                                          const unsigned int* __restrict__ csr,
                                          int beg0, int deg0, int maxs0,
                                          int beg1, int deg1, int maxs1,
                                          int lane, unsigned int sent,
                                          float2v* acc0, float2v* acc1) {
    int hbase = lane & 32;
    int hl = lane & 31;
    int j = (hl >> 3) & 3;
    unsigned int s8 = (unsigned int)((lane & 7) * 8);
    unsigned int idx0 = (hl < deg0) ? csr[beg0 + hl] : sent;
    unsigned int idx1 = (hl < deg1) ? csr[beg1 + hl] : sent;
    int lim0 = maxs0 > 32 ? 32 : maxs0;   // scalar
    int lim1 = maxs1 > 32 ? 32 : maxs1;   // scalar
    uint2v h0[8], h1[8];
    agg_issue8w(Hs, idx0, lim0, hbase, j, s8, h0);
    agg_issue8w(Hs, idx1, lim1, hbase, j, s8, h1);
    agg_cons8w(h0, lim0, acc0);
    agg_cons8w(h1, lim1, acc1);
    // rare deep tails (deg > 32)
    for (int base = 32; base < maxs0; base += 32) {
        unsigned int idx = (base + hl < deg0) ? csr[beg0 + base + hl] : sent;
        int lim = maxs0 - base; if (lim > 32) lim = 32;
        uint2v hh[8];
        agg_issue8w(Hs, idx, lim, hbase, j, s8, hh);
        agg_cons8w(hh, lim, acc0);
    }
    for (int base = 32; base < maxs1; base += 32) {
        unsigned int idx = (base + hl < deg1) ? csr[beg1 + base + hl] : sent;
        int lim = maxs1 - base; if (lim > 32) lim = 32;
        uint2v hh[8];
        agg_issue8w(Hs, idx, lim, hbase, j, s8, hh);
        agg_cons8w(hh, lim, acc1);
    }
    // merge the half's 4 subgroups (bits 3,4); does not cross halves
#pragma unroll
    for (int k = 0; k < 4; ++k) {
        float2v o;
        o.x = __shfl_xor(acc0[k].x, 8, 64);  o.y = __shfl_xor(acc0[k].y, 8, 64);
        acc0[k] += o;
        o.x = __shfl_xor(acc0[k].x, 16, 64); o.y = __shfl_xor(acc0[k].y, 16, 64);
        acc0[k] += o;
        o.x = __shfl_xor(acc1[k].x, 8, 64);  o.y = __shfl_xor(acc1[k].y, 8, 64);
        acc1[k] += o;
        o.x = __shfl_xor(acc1[k].x, 16, 64); o.y = __shfl_xor(acc1[k].y, 16, 64);
        acc1[k] += o;
    }
}

// layer-1 + fused GEMM2: block = 16 nodes (4 waves x 2 pairs). v = dinv *
// relu(b + dinv * agg); rows staged in LDS bf16 (XOR-swizzled at
// 8-element granularity), one barrier, each wave MFMAs one 16-col tile
// of W2, stores fp8 Hs2. Hs2 sentinel row N zeroed here (aliases temp).
__global__ __launch_bounds__(256, 8) void k_agg1(Ctx c0, Ctx c1, int nb0, int swz,
                                                 const float* __restrict__ bias,
                                                 const unsigned short* __restrict__ Wt2,
                                                 int n) {
    __shared__ unsigned short As[16][64];
    Ctx c; int b;
    agg_map(blockIdx.x, nb0, swz, c0, c1, c, b);
    int wave = threadIdx.x >> 6, lane = threadIdx.x & 63;
    int h = lane >> 5;
    int nbase = b * 16 + wave * 4;
    int node0 = nbase + h;
    int node1 = nbase + 2 + h;
    int nd0 = node0 < n ? node0 : 0;
    int nd1 = node1 < n ? node1 : 0;
    int beg0 = c.row_ptr[nd0];
    int beg1 = c.row_ptr[nd1];
    int deg0 = (node0 < n) ? c.degA[nd0] : 0;
    int deg1 = (node1 < n) ? c.degA[nd1] : 0;
    int od0 = __shfl_xor(deg0, 32, 64); int m0 = deg0 > od0 ? deg0 : od0;
    int od1 = __shfl_xor(deg1, 32, 64); int m1 = deg1 > od1 ? deg1 : od1;
    int maxs0 = __builtin_amdgcn_readfirstlane(m0);
    int maxs1 = __builtin_amdgcn_readfirstlane(m1);
    if (b == 0 && threadIdx.x < 64) c.Hs2[(size_t)n * 64 + threadIdx.x] = 0;
    float2v acc0[4] = {{0.f,0.f},{0.f,0.f},{0.f,0.f},{0.f,0.f}};
    float2v acc1[4] = {{0.f,0.f},{0.f,0.f},{0.f,0.f},{0.f,0.f}};
    agg_pair2(c.Hs, c.csr, beg0, deg0, maxs0, beg1, deg1, maxs1,
              lane, (unsigned int)n << 6, acc0, acc1);
    if (((lane >> 3) & 3) == 0) {          // first subgroup of each half
        int s = lane & 7;
#pragma unroll
        for (int pr = 0; pr < 2; ++pr) {
            const float2v* ac = pr ? acc1 : acc0;
            int node = nbase + pr * 2 + h;
            ushort4 oA = {0, 0, 0, 0}, oB = {0, 0, 0, 0};
            if (node < n) {
                uint2v hv = *(const uint2v*)(c.Hs + (size_t)node * 64 + s * 8);
                float2v h0 = up8lo(hv[0]), h1 = up8hi(hv[0]);
                float2v h2 = up8lo(hv[1]), h3 = up8hi(hv[1]);
                float4 ba = *(const float4*)(bias + s * 8);
                float4 bb = *(const float4*)(bias + s * 8 + 4);
                float d = c.dinv[node];
                oA.x = f2bf(fmaxf(ba.x + d * (ac[0].x + h0.x), 0.0f) * d);
                oA.y = f2bf(fmaxf(ba.y + d * (ac[0].y + h0.y), 0.0f) * d);
                oA.z = f2bf(fmaxf(ba.z + d * (ac[1].x + h1.x), 0.0f) * d);
                oA.w = f2bf(fmaxf(ba.w + d * (ac[1].y + h1.y), 0.0f) * d);
                oB.x = f2bf(fmaxf(bb.x + d * (ac[2].x + h2.x), 0.0f) * d);
                oB.y = f2bf(fmaxf(bb.y + d * (ac[2].y + h2.y), 0.0f) * d);
                oB.z = f2bf(fmaxf(bb.z + d * (ac[3].x + h3.x), 0.0f) * d);
                oB.w = f2bf(fmaxf(bb.w + d * (ac[3].y + h3.y), 0.0f) * d);
            }
            int row = wave * 4 + pr * 2 + h;
            int col = (s * 8) ^ ((row & 7) << 3);
            *(ushort4*)(&As[row][col]) = oA;       // swizzled (8-elem blocks)
            *(ushort4*)(&As[row][col + 4]) = oB;
        }
    }
    __syncthreads();
    // fused GEMM2: wave handles col-tile ct = wave; all 16 A rows valid.
    {
        int r = lane & 15, q = lane >> 4;
        int sw = (r & 7) << 3;
        short8 a0 = *(const short8*)(&As[r][(q * 8) ^ sw]);
        short8 a1 = *(const short8*)(&As[r][(q * 8 + 32) ^ sw]);
        const unsigned short* wp = Wt2 + (wave * 16 + r) * 64 + q * 8;
        short8 b0 = *(const short8*)(wp);
        short8 b1 = *(const short8*)(wp + 32);
        f32x4 acc2 = {0.0f, 0.0f, 0.0f, 0.0f};
        acc2 = __builtin_amdgcn_mfma_f32_16x16x32_bf16(a0, b0, acc2, 0, 0, 0);
        acc2 = __builtin_amdgcn_mfma_f32_16x16x32_bf16(a1, b1, acc2, 0, 0, 0);
#pragma unroll
        for (int reg = 0; reg < 4; ++reg) {
            int l = q * 4 + reg;                     // local row 0..15
            int row = b * 16 + l;
            if (row < n)
                c.Hs2[(size_t)row * 64 + wave * 16 + r] = f2fp8(acc2[reg]);
        }
    }
}

// layer-2: block = 16 nodes; block-reduce 16 relu'd rows and atomicAdd
// the 64-float row into P2[b & (P2R-1)] (colsum kernel deleted).
__global__ __launch_bounds__(256, 8) void k_agg2(Ctx c0, Ctx c1, int nb0, int swz,
                                                 const float* __restrict__ bias, int n) {
    __shared__ float red[16 * 64];
    Ctx c; int b;
    agg_map(blockIdx.x, nb0, swz, c0, c1, c, b);
    int wave = threadIdx.x >> 6, lane = threadIdx.x & 63;
    int h = lane >> 5;
    int nbase = b * 16 + wave * 4;
    int node0 = nbase + h;
    int node1 = nbase + 2 + h;
    int nd0 = node0 < n ? node0 : 0;
    int nd1 = node1 < n ? node1 : 0;
    int beg0 = c.row_ptr[nd0];
    int beg1 = c.row_ptr[nd1];
    int deg0 = (node0 < n) ? c.degA[nd0] : 0;
    int deg1 = (node1 < n) ? c.degA[nd1] : 0;
    int od0 = __shfl_xor(deg0, 32, 64); int m0 = deg0 > od0 ? deg0 : od0;
    int od1 = __shfl_xor(deg1, 32, 64); int m1 = deg1 > od1 ? deg1 : od1;
    int maxs0 = __builtin_amdgcn_readfirstlane(m0);
    int maxs1 = __builtin_amdgcn_readfirstlane(m1);
    float2v acc0[4] = {{0.f,0.f},{0.f,0.f},{0.f,0.f},{0.f,0.f}};
    float2v acc1[4] = {{0.f,0.f},{0.f,0.f},{0.f,0.f},{0.f,0.f}};
    agg_pair2(c.Hs2, c.csr, beg0, deg0, maxs0, beg1, deg1, maxs1,
              lane, (unsigned int)n << 6, acc0, acc1);
    if (((lane >> 3) & 3) == 0) {
        int s = lane & 7;
#pragma unroll
        for (int pr = 0; pr < 2; ++pr) {
            const float2v* ac = pr ? acc1 : acc0;
            int node = nbase + pr * 2 + h;
            float4 vA = {0.f, 0.f, 0.f, 0.f}, vB = {0.f, 0.f, 0.f, 0.f};
            if (node < n) {
                uint2v hv = *(const uint2v*)(c.Hs2 + (size_t)node * 64 + s * 8);
                float2v h0 = up8lo(hv[0]), h1 = up8hi(hv[0]);
                float2v h2 = up8lo(hv[1]), h3 = up8hi(hv[1]);
                float4 ba = *(const float4*)(bias + s * 8);
                float4 bb = *(const float4*)(bias + s * 8 + 4);
                float d = c.dinv[node];
                vA.x = fmaxf(ba.x + d * (ac[0].x + h0.x), 0.0f);
                vA.y = fmaxf(ba.y + d * (ac[0].y + h0.y), 0.0f);
                vA.z = fmaxf(ba.z + d * (ac[1].x + h1.x), 0.0f);
                vA.w = fmaxf(ba.w + d * (ac[1].y + h1.y), 0.0f);
                vB.x = fmaxf(bb.x + d * (ac[2].x + h2.x), 0.0f);
                vB.y = fmaxf(bb.y + d * (ac[2].y + h2.y), 0.0f);
                vB.z = fmaxf(bb.z + d * (ac[3].x + h3.x), 0.0f);
                vB.w = fmaxf(bb.w + d * (ac[3].y + h3.y), 0.0f);
            }
            int row = wave * 4 + pr * 2 + h;
            *(float4*)(&red[row * 64 + s * 8]) = vA;
            *(float4*)(&red[row * 64 + s * 8 + 4]) = vB;
        }
    }
    __syncthreads();
    if (threadIdx.x < 64) {
        float acc16 = 0.0f;
#pragma unroll
        for (int r = 0; r < 16; ++r) acc16 += red[r * 64 + threadIdx.x];
        atomicAdd(&c.P2[(b & (P2R - 1)) * 64 + threadIdx.x], acc16);
    }
}

// fc: 4-wave row-parallel reduce of P2, then out = fcb + (S/n) @ fcw^T
__global__ __launch_bounds__(256) void k_fc(Ctx c0, Ctx c1,
                                            const float* __restrict__ fcw,
                                            const float* __restrict__ fcb, int n) {
    Ctx c = blockIdx.x ? c1 : c0;
    __shared__ float Sp[4][64];
    int j = threadIdx.x & 63, g = threadIdx.x >> 6;
    float s = 0.0f;
    for (int r = g; r < P2R; r += 4) s += c.P2[r * 64 + j];
    Sp[g][j] = s;
    __syncthreads();
    if (threadIdx.x < 64) {
        float S = (Sp[0][j] + Sp[1][j]) + (Sp[2][j] + Sp[3][j]);
        Sp[0][j] = S * (1.0f / (float)n);
    }
    __syncthreads();
    if (threadIdx.x < 64) {
        float acc = fcb[j];
#pragma unroll
        for (int k = 0; k < 64; ++k) acc += Sp[0][k] * fcw[j * 64 + k];
        c.outp[j] = acc;
    }
}

extern "C" void kernel_launch(void* const* d_in, const int* in_sizes, int n_in,
                              void* d_out, int out_size, void* d_ws, size_t ws_size,
                              hipStream_t stream) {
    const float* x[2]  = {(const float*)d_in[0], (const float*)d_in[1]};
    const int*   ei[2] = {(const int*)d_in[2], (const int*)d_in[3]};
    const float* W1  = (const float*)d_in[4];
    const float* b1  = (const float*)d_in[5];
    const float* W2  = (const float*)d_in[6];
    const float* b2  = (const float*)d_in[7];
    const float* fcw = (const float*)d_in[8];
    const float* fcb = (const float*)d_in[9];
    float* out = (float*)d_out;

    const int N  = in_sizes[0] / 64;
    const int E  = in_sizes[2] / 2;
    const int NF = N * 64;
    const int K  = (N + CHUNK - 1) / CHUNK;     // 782 buckets
    const int gGm  = (N + 15) / 16;             // aggregate blocks (16 nodes each)
    const int gGmP = (gGm + 3) & ~3;            // padded so swizzle stays legal
    const int nTiles = (N + 15) / 16;
    const int gMf = (nTiles + 3) / 4;
    const int gBin = (E + EPB - 1) / EPB;
    const int gK  = (K + TPB - 1) / TPB;

    auto al = [](size_t x) { return (x + 127) & ~(size_t)127; };
    size_t tempB = (size_t)K * CAP * 4;
    size_t hs2B  = (size_t)NF + 64;                    // fp8 + sentinel row N
    size_t szRegion = al(tempB > hs2B ? tempB : hs2B); // Hs2 aliases temp
    size_t szHs  = al((size_t)NF + 64);                // fp8 + sentinel row N
    size_t szCsr = al((size_t)K * CAP * 4);            // bucket-major, stride CAP
    size_t szRp  = al((size_t)N * 4);                  // beg only
    size_t szDeg = al((size_t)N * 4);
    size_t szDi  = al((size_t)N * 4);
    size_t szCu  = al((size_t)K * CPAD * 4);           // padded cursors
    size_t szP2  = al((size_t)P2R * 64 * 4);
    size_t setB  = szRegion + szHs + szCsr + szRp + szDeg + szDi + szCu + szP2;
    size_t wtB   = 2 * al(64 * 64 * 2);
    bool batched = ws_size >= wtB + 2 * setB;

    char* base = (char*)d_ws;
    unsigned short* Wt1 = (unsigned short*)base;
    unsigned short* Wt2 = (unsigned short*)(base + al(64 * 64 * 2));

    auto mkctx = [&](int g, char* p) {
        Ctx c;
        c.X = x[g]; c.esrc = ei[g]; c.edst = ei[g] + E;
        c.temp = (unsigned int*)p; c.Hs2 = (unsigned char*)p; p += szRegion;
        c.Hs = (unsigned char*)p; p += szHs;
        c.csr = (unsigned int*)p; p += szCsr;
        c.row_ptr = (int*)p; p += szRp;
        c.degA = (int*)p; p += szDeg;
        c.dinv = (float*)p; p += szDi;
        c.cursorG = (int*)p; p += szCu;
        c.P2 = (float*)p;
        c.outp = out + g * 64;
        return c;
    };
    char* set0 = base + wtB;
    Ctx c0 = mkctx(0, set0);
    Ctx c1 = mkctx(1, batched ? set0 + setB : set0);   // fallback: shares set0

    k_prepW2<<<2, 256, 0, stream>>>(W1, W2, Wt1, Wt2);

    auto pipe = [&](Ctx A, Ctx B, int mult) {
        int swz = (mult == 2) ? 1 : 0;   // gGmP is always %4 == 0
        k_zeroCur<<<mult * gK, TPB, 0, stream>>>(A, B, gK, K, N);
        k_binA<<<mult * gBin, 1024, 0, stream>>>(A, B, gBin, E, K);
        k_csrb<<<mult * K, 256, 0, stream>>>(A, B, K, N);
        k_gemm1<<<mult * gMf, 256, 0, stream>>>(A, B, gMf, Wt1, nTiles, N);
        k_agg1<<<mult * gGmP, 256, 0, stream>>>(A, B, gGmP, swz, b1, Wt2, N);
        k_agg2<<<mult * gGmP, 256, 0, stream>>>(A, B, gGmP, swz, b2, N);
        k_fc<<<mult, 256, 0, stream>>>(A, B, fcw, fcb, N);
    };

    if (batched) {
        pipe(c0, c1, 2);
    } else {
        pipe(c0, c0, 1);   // sequential, shared buffer set
        pipe(c1, c1, 1);
    }
}

// Round 16
// 287.370 us; speedup vs baseline: 1.0530x; 1.0360x over previous
//
#include <hip/hip_runtime.h>

// SiameseGNN round 35: resubmit of R34 (infra failure:
// GPUAcquisitionTimeout -- no data, kernel unmeasured). No changes.
//
// Bisect the R28 regression -- revert the colsum bundle (agg2 P2 global
// atomics), keep binA rank-from-atomic.
// Evidence: R27=278.7; R28 consolidation=302.6; csrb scratch fix +
// gemm1 un-fuse recovered only ~5us (R33=297.7, agg1 at floor all
// rounds). Remaining suspects: (a) binA rank-from-returning-atomic,
// (b) colsum deleted via agg2 -> 800K global fp32 atomicAdds into a
// 128KB P2 region shared by 12.5K blocks across 8 XCDs. R24 lesson
// (100K atomics into 64 ints = 390us: cross-XCD serialization at the
// coherence point) makes (b) prime: same mechanism, ~1/20 severity
// ~= the unexplained ~19us. (a) is a strict instruction reduction
// with independent atomic chains -- structurally benign.
//   this round: agg2 writes its unique row P[b] (no atomics);
//   k_colsum restored (grid-stride partials, no atomics); fc reads
//   256 colsum rows with the 4-wave parallel form. binA keeps
//   rank-from-atomic; gemm1 standalone; csrb = R27. 8 dispatches.
// If total -> ~274-280: atomics were guilty, binA win banked.
// If total stays ~295: binA is guilty; next round reverts it.

#define TPB    256
#define CHUNK  128
#define SHIFT  7
#define KMAX   1024
#define CAP    2560
#define EPB    8192
#define CPAD   16      // cursorG stride (ints)

typedef __attribute__((ext_vector_type(8))) short short8;
typedef __attribute__((ext_vector_type(4))) float f32x4;
typedef __attribute__((ext_vector_type(2))) float float2v;
typedef __attribute__((ext_vector_type(2))) unsigned int uint2v;

struct Ctx {
    const float* X; const int* esrc; const int* edst;
    unsigned int* temp; unsigned char* Hs2; unsigned char* Hs;
    unsigned int* csr; int* row_ptr; int* degA; float* dinv; int* cursorG;
    float* P; float* P2; float* outp;
};

__device__ __forceinline__ unsigned short f2bf(float x) {
    union { float f; unsigned int i; } c; c.f = x;
    unsigned int r = c.i + 0x7FFFu + ((c.i >> 16) & 1u);   // RNE
    return (unsigned short)(r >> 16);
}
__device__ __forceinline__ unsigned char f2fp8(float x) {
    int p = __builtin_amdgcn_cvt_pk_fp8_f32(x, x, 0, false);
    return (unsigned char)(p & 0xFF);
}
__device__ __forceinline__ float2v up8lo(unsigned int w) {
    return __builtin_amdgcn_cvt_pk_f32_fp8(w, false);
}
__device__ __forceinline__ float2v up8hi(unsigned int w) {
    return __builtin_amdgcn_cvt_pk_f32_fp8(w, true);
}

__global__ void k_prepW2(const float* __restrict__ W1, const float* __restrict__ W2,
                         unsigned short* __restrict__ Wt1, unsigned short* __restrict__ Wt2) {
    const float* W = blockIdx.x ? W2 : W1;
    unsigned short* Wt = blockIdx.x ? Wt2 : Wt1;
    for (int i = threadIdx.x; i < 64 * 64; i += 256) {
        int n = i >> 6, k = i & 63;
        Wt[i] = f2bf(W[k * 64 + n]);
    }
}

// zero cursors + the Hs sentinel row (row N; ws re-poisoned per call)
__global__ void k_zeroCur(Ctx c0, Ctx c1, int nb0, int K, int N) {
    int b = blockIdx.x; Ctx c = c0;
    if (b >= nb0) { c = c1; b -= nb0; }
    int i = b * blockDim.x + threadIdx.x;
    if (i < K) c.cursorG[i * CPAD] = 0;
    if (b == 0 && threadIdx.x < 64) c.Hs[(size_t)N * 64 + threadIdx.x] = 0;
}

// binA: LDS counting sort per block, burst segment writes. 1024 threads.
// Rank captured from the histogram atomicAdd (packed dst|rank<<17);
// rd/rs live in registers (compile-time-indexed unrolled loops only).
__global__ __launch_bounds__(1024) void k_binA(Ctx c0, Ctx c1, int nb0, int E, int K) {
    __shared__ int cnt[KMAX];
    __shared__ int ofs[KMAX];
    __shared__ int segBase[KMAX];
    __shared__ int wsum[16];
    __shared__ unsigned int sorted[EPB];
    __shared__ unsigned short bkt[EPB];
    int b = blockIdx.x; Ctx c = c0;
    if (b >= nb0) { c = c1; b -= nb0; }
    int tid = threadIdx.x;               // 0..1023 == KMAX
    cnt[tid] = 0;
    __syncthreads();
    int base = b * EPB;
    int tot = E - base; if (tot > EPB) tot = EPB;
    unsigned int rd[EPB / 1024];
    unsigned int rs[EPB / 1024];
#pragma unroll
    for (int k = 0; k < EPB / 1024; ++k) {
        int e = base + k * 1024 + tid;
        rd[k] = 0xFFFFFFFFu; rs[k] = 0;
        if (e < E) {
            unsigned int dst = (unsigned int)c.edst[e];
            rs[k] = (unsigned int)c.esrc[e];
            unsigned int rk = (unsigned int)atomicAdd(&cnt[dst >> SHIFT], 1);
            rd[k] = dst | (rk << 17);    // dst:17 bits (N<131072), rank:13
        }
    }
    __syncthreads();
    int v = cnt[tid];
    int lane = tid & 63, w = tid >> 6;
    int x = v;                            // wave-inclusive scan
#pragma unroll
    for (int off = 1; off < 64; off <<= 1) {
        int t = __shfl_up(x, off, 64);
        if (lane >= off) x += t;
    }
    if (lane == 63) wsum[w] = x;
    __syncthreads();
    if (tid < 16) {
        int y = wsum[tid];
#pragma unroll
        for (int off = 1; off < 16; off <<= 1) {
            int t = __shfl_up(y, off, 16);
            if ((tid & 15) >= off) y += t;
        }
        wsum[tid] = y;                    // inclusive wave totals
    }
    __syncthreads();
    int pre = w ? wsum[w - 1] : 0;
    ofs[tid] = x + pre - v;               // exclusive scan
    if (tid < K) {
        segBase[tid] = v ? atomicAdd(&c.cursorG[tid * CPAD], v) : 0;
    } else {
        segBase[tid] = 0;
    }
    __syncthreads();
#pragma unroll
    for (int k = 0; k < EPB / 1024; ++k) {
        if (rd[k] != 0xFFFFFFFFu) {
            unsigned int dst = rd[k] & 0x1FFFFu;
            int rk = (int)(rd[k] >> 17);
            int bk = (int)(dst >> SHIFT);
            int p = ofs[bk] + rk;
            sorted[p] = ((dst & (CHUNK - 1)) << 17) | rs[k];
            bkt[p] = (unsigned short)bk;
        }
    }
    __syncthreads();
    for (int p = tid; p < tot; p += 1024) {
        unsigned int vv = sorted[p];
        int bk = bkt[p];
        int pos = segBase[bk] + (p - ofs[bk]);
        if (pos < CAP) c.temp[(size_t)bk * CAP + pos] = vv;
    }
}

// Per-bucket LDS counting sort -> bucket-major csr slice (stride CAP) +
// row_ptr (beg) + deg + dinv. Exact R27 form: tl[] staged during
// histogram (temp read once), scatter via cur[] LDS-atomic ranks.
__global__ __launch_bounds__(256) void k_csrb(Ctx c0, Ctx c1, int nb0, int N) {
    __shared__ int deg[CHUNK];
    __shared__ int lofs[CHUNK];
    __shared__ int cur[CHUNK];
    __shared__ int wsum2[2];
    __shared__ unsigned int tl[CAP];
    int b = blockIdx.x; Ctx c = c0;
    if (b >= nb0) { c = c1; b -= nb0; }
    int tid = threadIdx.x;
    if (tid < CHUNK) deg[tid] = 0;
    __syncthreads();
    int cnt = c.cursorG[b * CPAD]; if (cnt > CAP) cnt = CAP;
    const size_t tb = (size_t)b * CAP;
    for (int i = tid; i < cnt; i += 256) {
        unsigned int vv = c.temp[tb + i];
        tl[i] = vv;
        atomicAdd(&deg[vv >> 17], 1);
    }
    __syncthreads();
    int vdeg = 0, x = 0;
    if (tid < CHUNK) { vdeg = deg[tid]; x = vdeg; }
#pragma unroll
    for (int off = 1; off < 64; off <<= 1) {
        int t = __shfl_up(x, off, 64);
        if ((tid & 63) >= off) x += t;
    }
    if (tid < CHUNK && (tid & 63) == 63) wsum2[tid >> 6] = x;
    __syncthreads();
    int base = b * CAP;                  // bucket-major: no global scan needed
    if (tid < CHUNK) {
        int pre = (tid >> 6) ? wsum2[0] : 0;
        int excl = x + pre - vdeg;
        lofs[tid] = excl;
        cur[tid] = 0;
        int node = b * CHUNK + tid;
        if (node < N) {
            c.row_ptr[node] = base + excl;
            c.degA[node] = vdeg;
            c.dinv[node] = rsqrtf((float)vdeg + 1.0f);
        }
    }
    __syncthreads();
    for (int i = tid; i < cnt; i += 256) {
        unsigned int p = tl[i];
        int dl = p >> 17;
        int rank = atomicAdd(&cur[dl], 1);
        c.csr[base + lofs[dl] + rank] = (p & 0x1FFFFu) << 6;   // src byte offset
    }
}

// Shared MFMA body: A-fragments provided; B from Wt; store fp8 Hs.
__device__ __forceinline__ void mfma_tail(short8 a0, short8 a1,
                                          const unsigned short* __restrict__ Wt,
                                          unsigned char* __restrict__ Hs,
                                          int row0, int r, int q, int N) {
    short8 bfrag[4][2];
#pragma unroll
    for (int ct = 0; ct < 4; ++ct)
#pragma unroll
        for (int kb = 0; kb < 2; ++kb)
            bfrag[ct][kb] = *(const short8*)(Wt + (ct * 16 + r) * 64 + q * 8 + 32 * kb);
    f32x4 acc[4];
#pragma unroll
    for (int ct = 0; ct < 4; ++ct) {
        acc[ct] = (f32x4){0.0f, 0.0f, 0.0f, 0.0f};
        acc[ct] = __builtin_amdgcn_mfma_f32_16x16x32_bf16(a0, bfrag[ct][0], acc[ct], 0, 0, 0);
        acc[ct] = __builtin_amdgcn_mfma_f32_16x16x32_bf16(a1, bfrag[ct][1], acc[ct], 0, 0, 0);
    }
#pragma unroll
    for (int reg = 0; reg < 4; ++reg) {
        int row = row0 + q * 4 + reg;
        if (row < N) {
            size_t base = (size_t)row * 64 + r;
#pragma unroll
            for (int ct = 0; ct < 4; ++ct)
                Hs[base + ct * 16] = f2fp8(acc[ct][reg]);
        }
    }
}

// GEMM1 (standalone): fp32 X in, dinv folded into A-fragment conversion.
__global__ __launch_bounds__(256) void k_gemm1(Ctx c0, Ctx c1, int nb0,
                                               const unsigned short* __restrict__ Wt,
                                               int nTiles, int N) {
    int b = blockIdx.x; Ctx c = c0;
    if (b >= nb0) { c = c1; b -= nb0; }
    int wave = threadIdx.x >> 6, lane = threadIdx.x & 63;
    int tile = b * 4 + wave;
    if (tile >= nTiles) return;
    int r = lane & 15, q = lane >> 4;
    int row0 = tile * 16;
    int row = row0 + r;
    int rr = row < N ? row : N - 1;
    float d = c.dinv[rr];
    const float* xrow = c.X + (size_t)rr * 64 + q * 8;
    short8 a0, a1;
#pragma unroll
    for (int j = 0; j < 8; ++j) a0[j] = (short)f2bf(xrow[j] * d);
#pragma unroll
    for (int j = 0; j < 8; ++j) a1[j] = (short)f2bf(xrow[32 + j] * d);
    mfma_tail(a0, a1, Wt, c.Hs, row0, r, q, N);
}

// agg block mapping: XCD-partition swizzle (graph = (blockIdx>>2)&1) when
// swz, else linear split.
__device__ __forceinline__ void agg_map(int bi, int nb0, int swz,
                                        const Ctx& c0, const Ctx& c1,
                                        Ctx& c, int& b) {
    if (swz) {
        int graph = (bi >> 2) & 1;
        b = ((bi >> 3) << 2) | (bi & 3);
        c = graph ? c1 : c0;
    } else {
        b = bi; c = c0;
        if (b >= nb0) { c = c1; b -= nb0; }
    }
}

// 8-deep dwordx2 issue/consume windows; one window = 32 slots (4 edges
// per wave-instruction: 8 subgroups x 8 lanes x 8B). slotbase
// compile-time, lim scalar (SGPR).
__device__ __forceinline__ void agg_issue8w(const unsigned char* __restrict__ Hs,
                                            unsigned int idx, int lim,
                                            int hbase, int j, unsigned int s8,
                                            uint2v* h) {
#pragma unroll
    for (int u = 0; u < 8; ++u) {
        if (4 * u >= lim) break;              // SGPR cmp -> s_cbranch
        unsigned int su = (unsigned int)__shfl((int)idx, hbase + 4 * u + j, 64);
        h[u] = *(const uint2v*)(Hs + (su | s8));
    }
}
__device__ __forceinline__ void agg_cons8w(const uint2v* h, int lim, float2v* acc) {
#pragma unroll
    for (int u = 0; u < 8; ++u) {
        if (4 * u >= lim) break;
        acc[0] += up8lo(h[u][0]); acc[1] += up8hi(h[u][0]);   // sentinel adds 0
        acc[2] += up8lo(h[u][1]); acc[3] += up8hi(h[u][1]);
    }
}

// Two node-pairs per wave, pipelined: both cold idx loads overlap; both
// pairs' first windows are in flight before the first wait. Per half: 4
// subgroups x 8 lanes; lane s covers fp8 channels 8s..8s+7. csr holds
// src<<6; gather offset = su | (s*8). Invalid slots -> sentinel N<<6.
__device__ __forceinline__ void agg_pair2(const unsigned char* __restrict__ Hs,
                                          const unsigned int* __restrict__ csr,
                                          int beg0, int deg0, int maxs0,
                                          int beg1, int deg1, int maxs1,
                                          int lane, unsigned int sent,
                                          float2v* acc0, float2v* acc1) {
    int hbase = lane & 32;
    int hl = lane & 31;
    int j = (hl >> 3) & 3;
    unsigned int s8 = (unsigned int)((lane & 7) * 8);
    unsigned int idx0 = (hl < deg0) ? csr[beg0 + hl] : sent;
    unsigned int idx1 = (hl < deg1) ? csr[beg1 + hl] : sent;
    int lim0 = maxs0 > 32 ? 32 : maxs0;   // scalar
    int lim1 = maxs1 > 32 ? 32 : maxs1;   // scalar
    uint2v h0[8], h1[8];
    agg_issue8w(Hs, idx0, lim0, hbase, j, s8, h0);
    agg_issue8w(Hs, idx1, lim1, hbase, j, s8, h1);
    agg_cons8w(h0, lim0, acc0);
    agg_cons8w(h1, lim1, acc1);
    // rare deep tails (deg > 32)
    for (int base = 32; base < maxs0; base += 32) {
        unsigned int idx = (base + hl < deg0) ? csr[beg0 + base + hl] : sent;
        int lim = maxs0 - base; if (lim > 32) lim = 32;
        uint2v hh[8];
        agg_issue8w(Hs, idx, lim, hbase, j, s8, hh);
        agg_cons8w(hh, lim, acc0);
    }
    for (int base = 32; base < maxs1; base += 32) {
        unsigned int idx = (base + hl < deg1) ? csr[beg1 + base + hl] : sent;
        int lim = maxs1 - base; if (lim > 32) lim = 32;
        uint2v hh[8];
        agg_issue8w(Hs, idx, lim, hbase, j, s8, hh);
        agg_cons8w(hh, lim, acc1);
    }
    // merge the half's 4 subgroups (bits 3,4); does not cross halves
#pragma unroll
    for (int k = 0; k < 4; ++k) {
        float2v o;
        o.x = __shfl_xor(acc0[k].x, 8, 64);  o.y = __shfl_xor(acc0[k].y, 8, 64);
        acc0[k] += o;
        o.x = __shfl_xor(acc0[k].x, 16, 64); o.y = __shfl_xor(acc0[k].y, 16, 64);
        acc0[k] += o;
        o.x = __shfl_xor(acc1[k].x, 8, 64);  o.y = __shfl_xor(acc1[k].y, 8, 64);
        acc1[k] += o;
        o.x = __shfl_xor(acc1[k].x, 16, 64); o.y = __shfl_xor(acc1[k].y, 16, 64);
        acc1[k] += o;
    }
}

// layer-1 + fused GEMM2: block = 16 nodes (4 waves x 2 pairs). v = dinv *
// relu(b + dinv * agg); rows staged in LDS bf16 (XOR-swizzled at
// 8-element granularity), one barrier, each wave MFMAs one 16-col tile
// of W2, stores fp8 Hs2. Hs2 sentinel row N zeroed here (aliases temp).
__global__ __launch_bounds__(256, 8) void k_agg1(Ctx c0, Ctx c1, int nb0, int swz,
                                                 const float* __restrict__ bias,
                                                 const unsigned short* __restrict__ Wt2,
                                                 int n) {
    __shared__ unsigned short As[16][64];
    Ctx c; int b;
    agg_map(blockIdx.x, nb0, swz, c0, c1, c, b);
    int wave = threadIdx.x >> 6, lane = threadIdx.x & 63;
    int h = lane >> 5;
    int nbase = b * 16 + wave * 4;
    int node0 = nbase + h;
    int node1 = nbase + 2 + h;
    int nd0 = node0 < n ? node0 : 0;
    int nd1 = node1 < n ? node1 : 0;
    int beg0 = c.row_ptr[nd0];
    int beg1 = c.row_ptr[nd1];
    int deg0 = (node0 < n) ? c.degA[nd0] : 0;
    int deg1 = (node1 < n) ? c.degA[nd1] : 0;
    int od0 = __shfl_xor(deg0, 32, 64); int m0 = deg0 > od0 ? deg0 : od0;
    int od1 = __shfl_xor(deg1, 32, 64); int m1 = deg1 > od1 ? deg1 : od1;
    int maxs0 = __builtin_amdgcn_readfirstlane(m0);
    int maxs1 = __builtin_amdgcn_readfirstlane(m1);
    if (b == 0 && threadIdx.x < 64) c.Hs2[(size_t)n * 64 + threadIdx.x] = 0;
    float2v acc0[4] = {{0.f,0.f},{0.f,0.f},{0.f,0.f},{0.f,0.f}};
    float2v acc1[4] = {{0.f,0.f},{0.f,0.f},{0.f,0.f},{0.f,0.f}};
    agg_pair2(c.Hs, c.csr, beg0, deg0, maxs0, beg1, deg1, maxs1,
              lane, (unsigned int)n << 6, acc0, acc1);
    if (((lane >> 3) & 3) == 0) {          // first subgroup of each half
        int s = lane & 7;
#pragma unroll
        for (int pr = 0; pr < 2; ++pr) {
            const float2v* ac = pr ? acc1 : acc0;
            int node = nbase + pr * 2 + h;
            ushort4 oA = {0, 0, 0, 0}, oB = {0, 0, 0, 0};
            if (node < n) {
                uint2v hv = *(const uint2v*)(c.Hs + (size_t)node * 64 + s * 8);
                float2v h0 = up8lo(hv[0]), h1 = up8hi(hv[0]);
                float2v h2 = up8lo(hv[1]), h3 = up8hi(hv[1]);
                float4 ba = *(const float4*)(bias + s * 8);
                float4 bb = *(const float4*)(bias + s * 8 + 4);
                float d = c.dinv[node];
                oA.x = f2bf(fmaxf(ba.x + d * (ac[0].x + h0.x), 0.0f) * d);
                oA.y = f2bf(fmaxf(ba.y + d * (ac[0].y + h0.y), 0.0f) * d);
                oA.z = f2bf(fmaxf(ba.z + d * (ac[1].x + h1.x), 0.0f) * d);
                oA.w = f2bf(fmaxf(ba.w + d * (ac[1].y + h1.y), 0.0f) * d);
                oB.x = f2bf(fmaxf(bb.x + d * (ac[2].x + h2.x), 0.0f) * d);
                oB.y = f2bf(fmaxf(bb.y + d * (ac[2].y + h2.y), 0.0f) * d);
                oB.z = f2bf(fmaxf(bb.z + d * (ac[3].x + h3.x), 0.0f) * d);
                oB.w = f2bf(fmaxf(bb.w + d * (ac[3].y + h3.y), 0.0f) * d);
            }
            int row = wave * 4 + pr * 2 + h;
            int col = (s * 8) ^ ((row & 7) << 3);
            *(ushort4*)(&As[row][col]) = oA;       // swizzled (8-elem blocks)
            *(ushort4*)(&As[row][col + 4]) = oB;
        }
    }
    __syncthreads();
    // fused GEMM2: wave handles col-tile ct = wave; all 16 A rows valid.
    {
        int r = lane & 15, q = lane >> 4;
        int sw = (r & 7) << 3;
        short8 a0 = *(const short8*)(&As[r][(q * 8) ^ sw]);
        short8 a1 = *(const short8*)(&As[r][(q * 8 + 32) ^ sw]);
        const unsigned short* wp = Wt2 + (wave * 16 + r) * 64 + q * 8;
        short8 b0 = *(const short8*)(wp);
        short8 b1 = *(const short8*)(wp + 32);
        f32x4 acc2 = {0.0f, 0.0f, 0.0f, 0.0f};
        acc2 = __builtin_amdgcn_mfma_f32_16x16x32_bf16(a0, b0, acc2, 0, 0, 0);
        acc2 = __builtin_amdgcn_mfma_f32_16x16x32_bf16(a1, b1, acc2, 0, 0, 0);
#pragma unroll
        for (int reg = 0; reg < 4; ++reg) {
            int l = q * 4 + reg;                     // local row 0..15
            int row = b * 16 + l;
            if (row < n)
                c.Hs2[(size_t)row * 64 + wave * 16 + r] = f2fp8(acc2[reg]);
        }
    }
}

// layer-2: block = 16 nodes; block-reduce 16 relu'd rows -> P[block, f]
// (unique row per block, no atomics; gathers from Hs2)
__global__ __launch_bounds__(256, 8) void k_agg2(Ctx c0, Ctx c1, int nb0, int swz,
                                                 const float* __restrict__ bias, int n) {
    __shared__ float red[16 * 64];
    Ctx c; int b;
    agg_map(blockIdx.x, nb0, swz, c0, c1, c, b);
    int wave = threadIdx.x >> 6, lane = threadIdx.x & 63;
    int h = lane >> 5;
    int nbase = b * 16 + wave * 4;
    int node0 = nbase + h;
    int node1 = nbase + 2 + h;
    int nd0 = node0 < n ? node0 : 0;
    int nd1 = node1 < n ? node1 : 0;
    int beg0 = c.row_ptr[nd0];
    int beg1 = c.row_ptr[nd1];
    int deg0 = (node0 < n) ? c.degA[nd0] : 0;
    int deg1 = (node1 < n) ? c.degA[nd1] : 0;
    int od0 = __shfl_xor(deg0, 32, 64); int m0 = deg0 > od0 ? deg0 : od0;
    int od1 = __shfl_xor(deg1, 32, 64); int m1 = deg1 > od1 ? deg1 : od1;
    int maxs0 = __builtin_amdgcn_readfirstlane(m0);
    int maxs1 = __builtin_amdgcn_readfirstlane(m1);
    float2v acc0[4] = {{0.f,0.f},{0.f,0.f},{0.f,0.f},{0.f,0.f}};
    float2v acc1[4] = {{0.f,0.f},{0.f,0.f},{0.f,0.f},{0.f,0.f}};
    agg_pair2(c.Hs2, c.csr, beg0, deg0, maxs0, beg1, deg1, maxs1,
              lane, (unsigned int)n << 6, acc0, acc1);
    if (((lane >> 3) & 3) == 0) {
        int s = lane & 7;
#pragma unroll
        for (int pr = 0; pr < 2; ++pr) {
            const float2v* ac = pr ? acc1 : acc0;
            int node = nbase + pr * 2 + h;
            float4 vA = {0.f, 0.f, 0.f, 0.f}, vB = {0.f, 0.f, 0.f, 0.f};
            if (node < n) {
                uint2v hv = *(const uint2v*)(c.Hs2 + (size_t)node * 64 + s * 8);
                float2v h0 = up8lo(hv[0]), h1 = up8hi(hv[0]);
                float2v h2 = up8lo(hv[1]), h3 = up8hi(hv[1]);
                float4 ba = *(const float4*)(bias + s * 8);
                float4 bb = *(const float4*)(bias + s * 8 + 4);
                float d = c.dinv[node];
                vA.x = fmaxf(ba.x + d * (ac[0].x + h0.x), 0.0f);
                vA.y = fmaxf(ba.y + d * (ac[0].y + h0.y), 0.0f);
                vA.z = fmaxf(ba.z + d * (ac[1].x + h1.x), 0.0f);
                vA.w = fmaxf(ba.w + d * (ac[1].y + h1.y), 0.0f);
                vB.x = fmaxf(bb.x + d * (ac[2].x + h2.x), 0.0f);
                vB.y = fmaxf(bb.y + d * (ac[2].y + h2.y), 0.0f);
                vB.z = fmaxf(bb.z + d * (ac[3].x + h3.x), 0.0f);
                vB.w = fmaxf(bb.w + d * (ac[3].y + h3.y), 0.0f);
            }
            int row = wave * 4 + pr * 2 + h;
            *(float4*)(&red[row * 64 + s * 8]) = vA;
            *(float4*)(&red[row * 64 + s * 8 + 4]) = vB;
        }
    }
    __syncthreads();
    if (threadIdx.x < 64) {
        float acc16 = 0.0f;
#pragma unroll
        for (int r = 0; r < 16; ++r) acc16 += red[r * 64 + threadIdx.x];
        c.P[(size_t)b * 64 + threadIdx.x] = acc16;
    }
}

// colsum -> per-block partials in P2 (no atomics, no zero pass)
__global__ void k_colsum(Ctx c0, Ctx c1, int nb0, int rows) {
    int b = blockIdx.x; Ctx c = c0;
    if (b >= nb0) { c = c1; b -= nb0; }
    int f = threadIdx.x;  // 64
    float acc = 0.0f;
    for (int r = b; r < rows; r += nb0) acc += c.P[(size_t)r * 64 + f];
    c.P2[b * 64 + f] = acc;
}

// fc: 4-wave row-parallel reduce of the 256 colsum rows, then
// out = fcb + (S/n) @ fcw^T
__global__ __launch_bounds__(256) void k_fc(Ctx c0, Ctx c1,
                                            const float* __restrict__ fcw,
                                            const float* __restrict__ fcb, int n) {
    Ctx c = blockIdx.x ? c1 : c0;
    __shared__ float Sp[4][64];
    int j = threadIdx.x & 63, g = threadIdx.x >> 6;
    float s = 0.0f;
    for (int r = g; r < 256; r += 4) s += c.P2[r * 64 + j];
    Sp[g][j] = s;
    __syncthreads();
    if (threadIdx.x < 64) {
        float S = (Sp[0][j] + Sp[1][j]) + (Sp[2][j] + Sp[3][j]);
        Sp[0][j] = S * (1.0f / (float)n);
    }
    __syncthreads();
    if (threadIdx.x < 64) {
        float acc = fcb[j];
#pragma unroll
        for (int k = 0; k < 64; ++k) acc += Sp[0][k] * fcw[j * 64 + k];
        c.outp[j] = acc;
    }
}

extern "C" void kernel_launch(void* const* d_in, const int* in_sizes, int n_in,
                              void* d_out, int out_size, void* d_ws, size_t ws_size,
                              hipStream_t stream) {
    const float* x[2]  = {(const float*)d_in[0], (const float*)d_in[1]};
    const int*   ei[2] = {(const int*)d_in[2], (const int*)d_in[3]};
    const float* W1  = (const float*)d_in[4];
    const float* b1  = (const float*)d_in[5];
    const float* W2  = (const float*)d_in[6];
    const float* b2  = (const float*)d_in[7];
    const float* fcw = (const float*)d_in[8];
    const float* fcb = (const float*)d_in[9];
    float* out = (float*)d_out;

    const int N  = in_sizes[0] / 64;
    const int E  = in_sizes[2] / 2;
    const int NF = N * 64;
    const int K  = (N + CHUNK - 1) / CHUNK;     // 782 buckets
    const int gGm  = (N + 15) / 16;             // aggregate blocks (16 nodes each)
    const int gGmP = (gGm + 3) & ~3;            // padded so swizzle stays legal
    const int nTiles = (N + 15) / 16;
    const int gMf = (nTiles + 3) / 4;
    const int gBin = (E + EPB - 1) / EPB;
    const int gK  = (K + TPB - 1) / TPB;

    auto al = [](size_t x) { return (x + 127) & ~(size_t)127; };
    size_t tempB = (size_t)K * CAP * 4;
    size_t hs2B  = (size_t)NF + 64;                    // fp8 + sentinel row N
    size_t szRegion = al(tempB > hs2B ? tempB : hs2B); // Hs2 aliases temp
    size_t szHs  = al((size_t)NF + 64);                // fp8 + sentinel row N
    size_t szCsr = al((size_t)K * CAP * 4);            // bucket-major, stride CAP
    size_t szRp  = al((size_t)N * 4);                  // beg only
    size_t szDeg = al((size_t)N * 4);
    size_t szDi  = al((size_t)N * 4);
    size_t szCu  = al((size_t)K * CPAD * 4);           // padded cursors
    size_t szP   = al((size_t)gGmP * 64 * 4);
    size_t szP2  = al((size_t)256 * 64 * 4);
    size_t setB  = szRegion + szHs + szCsr + szRp + szDeg + szDi + szCu + szP + szP2;
    size_t wtB   = 2 * al(64 * 64 * 2);
    bool batched = ws_size >= wtB + 2 * setB;

    char* base = (char*)d_ws;
    unsigned short* Wt1 = (unsigned short*)base;
    unsigned short* Wt2 = (unsigned short*)(base + al(64 * 64 * 2));

    auto mkctx = [&](int g, char* p) {
        Ctx c;
        c.X = x[g]; c.esrc = ei[g]; c.edst = ei[g] + E;
        c.temp = (unsigned int*)p; c.Hs2 = (unsigned char*)p; p += szRegion;
        c.Hs = (unsigned char*)p; p += szHs;
        c.csr = (unsigned int*)p; p += szCsr;
        c.row_ptr = (int*)p; p += szRp;
        c.degA = (int*)p; p += szDeg;
        c.dinv = (float*)p; p += szDi;
        c.cursorG = (int*)p; p += szCu;
        c.P = (float*)p; p += szP;
        c.P2 = (float*)p;
        c.outp = out + g * 64;
        return c;
    };
    char* set0 = base + wtB;
    Ctx c0 = mkctx(0, set0);
    Ctx c1 = mkctx(1, batched ? set0 + setB : set0);   // fallback: shares set0

    k_prepW2<<<2, 256, 0, stream>>>(W1, W2, Wt1, Wt2);

    auto pipe = [&](Ctx A, Ctx B, int mult) {
        int swz = (mult == 2) ? 1 : 0;   // gGmP is always %4 == 0
        k_zeroCur<<<mult * gK, TPB, 0, stream>>>(A, B, gK, K, N);
        k_binA<<<mult * gBin, 1024, 0, stream>>>(A, B, gBin, E, K);
        k_csrb<<<mult * K, 256, 0, stream>>>(A, B, K, N);
        k_gemm1<<<mult * gMf, 256, 0, stream>>>(A, B, gMf, Wt1, nTiles, N);
        k_agg1<<<mult * gGmP, 256, 0, stream>>>(A, B, gGmP, swz, b1, Wt2, N);
        k_agg2<<<mult * gGmP, 256, 0, stream>>>(A, B, gGmP, swz, b2, N);
        k_colsum<<<mult * 256, 64, 0, stream>>>(A, B, 256, gGmP);
        k_fc<<<mult, 256, 0, stream>>>(A, B, fcw, fcb, N);
    };

    if (batched) {
        pipe(c0, c1, 2);
    } else {
        pipe(c0, c0, 1);   // sequential, shared buffer set
        pipe(c1, c1, 1);
    }
}